// Round 7
// baseline (503.233 us; speedup 1.0000x reference)
//
#include <hip/hip_runtime.h>
#include <math.h>

// Problem constants (from reference)
constexpr int NN   = 50000;   // nodes
constexpr int EE   = 300000;  // edges
constexpr int IND  = 1024;    // IN_DIM
constexpr int CODE = 768;     // CODE_DIM
constexpr int HID  = 256;

typedef __bf16 bf16_t;
typedef bf16_t bf16x8 __attribute__((ext_vector_type(8)));
typedef float  f32x4  __attribute__((ext_vector_type(4)));

__device__ __forceinline__ f32x4 mfma16(bf16x8 a, bf16x8 b, f32x4 c) {
    return __builtin_amdgcn_mfma_f32_16x16x32_bf16(a, b, c, 0, 0, 0);
}

// async global->LDS, 16B per lane, wave-uniform LDS base + lane*16
#define GLOAD_LDS16(gp, lp) __builtin_amdgcn_global_load_lds(                         \
    (__attribute__((address_space(1))) void*)(gp),                                    \
    (__attribute__((address_space(3))) void*)(lp), 16, 0, 0)

// counted-vmcnt barrier: tile-t loads (8/wave, issued one iter ago) are done;
// tile-t+1 loads (just issued) stay in flight across the barrier.
__device__ __forceinline__ void wait_stage(bool more) {
    if (more) asm volatile("s_waitcnt vmcnt(8)" ::: "memory");
    else      asm volatile("s_waitcnt vmcnt(0)" ::: "memory");
    __builtin_amdgcn_s_barrier();
    __builtin_amdgcn_sched_barrier(0);   // pin ds_reads after the barrier
}

// convert 8 fp32 -> hi/lo bf16 split (v = hi + lo, |lo| ~ 2^-8 |v|)
__device__ __forceinline__ void cvt_split(f32x4 u0, f32x4 u1, bf16x8& hi, bf16x8& lo) {
    #pragma unroll
    for (int i = 0; i < 4; i++) {
        bf16_t h0 = (bf16_t)u0[i];
        hi[i]     = h0;
        lo[i]     = (bf16_t)(u0[i] - (float)h0);
        bf16_t h1 = (bf16_t)u1[i];
        hi[4 + i] = h1;
        lo[4 + i] = (bf16_t)(u1[i] - (float)h1);
    }
}

// ---------------------------------------------------------------------------
// Stage 1: per-column sum/sumsq of x[:, 768:1024]
__global__ void colstats_kernel(const float* __restrict__ x, float* __restrict__ sums) {
    int col = threadIdx.x;             // 0..255
    float s = 0.f, s2 = 0.f;
    for (int row = blockIdx.x; row < NN; row += gridDim.x) {
        float v = x[(size_t)row * IND + CODE + col];
        s += v; s2 += v * v;
    }
    atomicAdd(&sums[col], s);
    atomicAdd(&sums[256 + col], s2);
}

__global__ void finalize_stats_kernel(const float* __restrict__ sums, float* __restrict__ mi) {
    int c = threadIdx.x;
    float mean = sums[c] / (float)NN;
    float var  = (sums[256 + c] - (float)NN * mean * mean) / (float)(NN - 1);
    float sd   = sqrtf(fmaxf(var, 0.f));
    sd = fmaxf(sd, 1e-6f);
    mi[c]       = mean;
    mi[256 + c] = 1.f / sd;
}

// Build Wmod (GEMM-ordered, numeric part pre-scaled) pre-split to bf16 hi/lo,
// and cb = b - d.
__global__ void prep_w_kernel(const float* __restrict__ W, const float* __restrict__ stats,
                              const float* __restrict__ b_in, bf16_t* __restrict__ Wh,
                              bf16_t* __restrict__ Wl, float* __restrict__ cb)
{
    int c = blockIdx.x, t = threadIdx.x;      // 256 blocks x 256 threads
    const float* wr = W + (size_t)c * IND;
    bf16_t* wh = Wh + (size_t)c * IND;
    bf16_t* wl = Wl + (size_t)c * IND;
    for (int k = t; k < 768; k += 256) {
        float v = wr[256 + k];
        bf16_t h = (bf16_t)v;
        wh[k] = h; wl[k] = (bf16_t)(v - (float)h);
    }
    {
        float v = wr[t] * stats[256 + t];
        bf16_t h = (bf16_t)v;
        wh[768 + t] = h; wl[768 + t] = (bf16_t)(v - (float)h);
    }
    float p = wr[t] * stats[256 + t] * stats[t];
    #pragma unroll
    for (int off = 32; off; off >>= 1) p += __shfl_xor(p, off);
    __shared__ float ps[4];
    if ((t & 63) == 0) ps[t >> 6] = p;
    __syncthreads();
    if (t == 0) cb[c] = b_in[c] - (ps[0] + ps[1] + ps[2] + ps[3]);
}

// small weights (256x256) -> bf16 hi/lo
__global__ void prep_ws_kernel(const float* __restrict__ W, bf16_t* __restrict__ Wh,
                               bf16_t* __restrict__ Wl)
{
    int c = blockIdx.x, t = threadIdx.x;
    float v = W[(size_t)c * 256 + t];
    bf16_t h = (bf16_t)v;
    Wh[(size_t)c * 256 + t] = h;
    Wl[(size_t)c * 256 + t] = (bf16_t)(v - (float)h);
}

// ---------------------------------------------------------------------------
// MFMA GEMM, split-bf16 (3 MFMAs), global_load_lds staging, double-buffered,
// counted-vmcnt pipeline (loads stay in flight across barriers).
// MODE 1: A = x, B = Wmod; in-loop row L2-norm of code cols applied at t==24;
//         epilogue relu(acc+cb).
// FATTN 1: epilogue computes attention logits al_s/al_d (wave == one head).
// Tile 128x128, BK=32, 256 threads = 4 waves (2x2), 64x64 per wave.

__device__ __forceinline__ void stage_a(const float* __restrict__ src, int ldk,
                                        int rowbase, int maxrow, int k0,
                                        float* ldsbuf, int tid) {
    int w = tid >> 6, l = tid & 63;
    int lr = l >> 3, lc = l & 7;
    int g  = lc ^ lr;                      // swizzled source chunk (row&7 == lr)
    #pragma unroll
    for (int i = 0; i < 4; i++) {
        int rloc = i * 32 + w * 8;
        float* dst = ldsbuf + rloc * 32;   // wave-uniform base
        int row = rowbase + rloc + lr;
        if (row > maxrow) row = maxrow;
        const float* gp = src + (size_t)row * ldk + k0 + g * 4;
        GLOAD_LDS16(gp, dst);
    }
}

// stage 128x32 bf16 tile; LDS slot p of col holds global chunk p^((col>>1)&3)
__device__ __forceinline__ void stage_b(const bf16_t* __restrict__ src, int n0, int ldk,
                                        int k0, bf16_t* buf, int tid) {
    int w = tid >> 6, l = tid & 63;
    #pragma unroll
    for (int i = 0; i < 2; i++) {
        int gbase = w * 128 + i * 64;
        bf16_t* dst = buf + gbase * 8;     // wave-uniform base (granule*8 bf16)
        int g = gbase + l;
        int col = g >> 2, p = g & 3;
        int gs = p ^ ((col >> 1) & 3);
        const bf16_t* gp = src + (size_t)(n0 + col) * ldk + k0 + gs * 8;
        GLOAD_LDS16(gp, dst);
    }
}

template<int MODE, int K, int FATTN>
__global__ __launch_bounds__(256) void gemm_mfma_kernel(
    const float* __restrict__ A, const bf16_t* __restrict__ Bh,
    const bf16_t* __restrict__ Bl, const float* __restrict__ cb,
    const float* __restrict__ a_src, const float* __restrict__ a_dst,
    float* __restrict__ out, float* __restrict__ al_s, float* __restrict__ al_d)
{
    __shared__ float  As[2][128 * 32];     // 32 KB
    __shared__ bf16_t Bhs[2][128 * 32];    // 16 KB
    __shared__ bf16_t Bls[2][128 * 32];    // 16 KB
    constexpr int NT = K / 32;

    int tid  = threadIdx.x;
    int lane = tid & 63;
    int w    = tid >> 6;
    int wr   = w >> 1, wc = w & 1;
    int r0   = blockIdx.x * 128, n0 = blockIdx.y * 128;

    f32x4 acc[4][4];
    #pragma unroll
    for (int i = 0; i < 4; i++)
        #pragma unroll
        for (int j = 0; j < 4; j++) acc[i][j] = (f32x4)0.f;

    float ss[4] = {0.f, 0.f, 0.f, 0.f};    // MODE1: row sumsq of code cols

    int kc = lane >> 4, fr = lane & 15;    // kc doubles as fq in epilogue

    stage_a(A, K, r0, NN - 1, 0, As[0], tid);
    stage_b(Bh, n0, K, 0, Bhs[0], tid);
    stage_b(Bl, n0, K, 0, Bls[0], tid);

    for (int t = 0; t < NT; ++t) {
        int buf = t & 1;
        bool more = (t + 1 < NT);
        if (more) {   // issue next tile; stays in flight across the barrier
            stage_a(A, K, r0, NN - 1, (t + 1) * 32, As[buf ^ 1], tid);
            stage_b(Bh, n0, K, (t + 1) * 32, Bhs[buf ^ 1], tid);
            stage_b(Bl, n0, K, (t + 1) * 32, Bls[buf ^ 1], tid);
        }
        wait_stage(more);   // vmcnt(8): only tile-t loads drained; + s_barrier

        if (MODE == 1 && t == 24) {
            // kap==768: code segment closed; scale acc rows by 1/||code row||
            #pragma unroll
            for (int mf = 0; mf < 4; mf++) {
                float s2 = ss[mf];
                s2 += __shfl_xor(s2, 16);
                s2 += __shfl_xor(s2, 32);   // full row sumsq (row wr*64+mf*16+fr)
                #pragma unroll
                for (int j = 0; j < 4; j++) {
                    float sv = __shfl(s2, kc * 4 + j);   // row ... + kc*4 + j
                    float iv = 1.f / fmaxf(sqrtf(sv), 1e-12f);
                    #pragma unroll
                    for (int nf = 0; nf < 4; nf++) acc[mf][nf][j] *= iv;
                }
            }
        }
        // ---- fragments + MFMA ----
        const float*  Ab = As[buf];
        const bf16_t* Hb = Bhs[buf];
        const bf16_t* Lb = Bls[buf];
        bf16x8 ahi[4], alo[4];
        #pragma unroll
        for (int mf = 0; mf < 4; mf++) {
            int r  = wr * 64 + mf * 16 + fr;
            int rb = r * 32, r7 = r & 7;
            f32x4 u0 = *(const f32x4*)&Ab[rb + (((2 * kc + 0) ^ r7) << 2)];
            f32x4 u1 = *(const f32x4*)&Ab[rb + (((2 * kc + 1) ^ r7) << 2)];
            if (MODE == 1 && t < 24) {
                #pragma unroll
                for (int q = 0; q < 4; q++) ss[mf] += u0[q] * u0[q] + u1[q] * u1[q];
            }
            cvt_split(u0, u1, ahi[mf], alo[mf]);
        }
        #pragma unroll
        for (int nf = 0; nf < 4; nf++) {
            int c  = wc * 64 + nf * 16 + fr;
            int pr = kc ^ ((c >> 1) & 3);
            bf16x8 bhi = *(const bf16x8*)&Hb[c * 32 + pr * 8];
            bf16x8 blo = *(const bf16x8*)&Lb[c * 32 + pr * 8];
            #pragma unroll
            for (int mf = 0; mf < 4; mf++) {
                acc[mf][nf] = mfma16(ahi[mf], bhi, acc[mf][nf]);
                acc[mf][nf] = mfma16(alo[mf], bhi, acc[mf][nf]);
                acc[mf][nf] = mfma16(ahi[mf], blo, acc[mf][nf]);
            }
        }
        __builtin_amdgcn_s_barrier();   // all waves done reading buf[t&1]
    }

    // ---- epilogue (+ optional fused attention logits; wave == one head) ----
    int head = blockIdx.y * 2 + wc;
    float asv[4], adv[4];
    if (FATTN) {
        #pragma unroll
        for (int nf = 0; nf < 4; nf++) {
            asv[nf] = a_src[head * 64 + nf * 16 + fr];
            adv[nf] = a_dst[head * 64 + nf * 16 + fr];
        }
    }
    #pragma unroll
    for (int mf = 0; mf < 4; mf++) {
        #pragma unroll
        for (int j = 0; j < 4; j++) {
            int row = r0 + wr * 64 + mf * 16 + kc * 4 + j;
            bool ok = row < NN;
            float s = 0.f, d = 0.f;
            #pragma unroll
            for (int nf = 0; nf < 4; nf++) {
                int col = n0 + wc * 64 + nf * 16 + fr;
                float v = acc[mf][nf][j];
                if (MODE == 1) v = fmaxf(v + cb[col], 0.f);
                if (ok) out[(size_t)row * HID + col] = v;
                if (FATTN) { s += v * asv[nf]; d += v * adv[nf]; }
            }
            if (FATTN) {
                #pragma unroll
                for (int off = 1; off < 16; off <<= 1) {
                    s += __shfl_xor(s, off);
                    d += __shfl_xor(d, off);
                }
                if (ok && fr == 0) {
                    al_s[row * 4 + head] = s;
                    al_d[row * 4 + head] = d;
                }
            }
        }
    }
}

// ---------------------------------------------------------------------------
// CSR build (by destination)
__global__ void deg_kernel(const int* __restrict__ ei, int* __restrict__ deg) {
    int e = blockIdx.x * 256 + threadIdx.x;
    if (e < EE) atomicAdd(&deg[ei[EE + e]], 1);
}

constexpr int SCB = 1024;                       // elems per scan block
constexpr int SCN = (NN + SCB - 1) / SCB;       // 49

__global__ void scan_pass1(const int* __restrict__ deg, int* __restrict__ bsum) {
    int b = blockIdx.x, t = threadIdx.x;
    int base = b * SCB + t * 4;
    int s = 0;
    #pragma unroll
    for (int i = 0; i < 4; i++) { int idx = base + i; if (idx < NN) s += deg[idx]; }
    #pragma unroll
    for (int off = 32; off; off >>= 1) s += __shfl_xor(s, off);
    __shared__ int ps[4];
    if ((t & 63) == 0) ps[t >> 6] = s;
    __syncthreads();
    if (t == 0) bsum[b] = ps[0] + ps[1] + ps[2] + ps[3];
}

__global__ void scan_pass2(int* __restrict__ bsum) {   // 1 block, 64 threads
    int t = threadIdx.x;
    int orig = (t < SCN) ? bsum[t] : 0;
    int v = orig;
    for (int off = 1; off < 64; off <<= 1) {
        int u = __shfl_up(v, off);
        if (t >= off) v += u;
    }
    if (t < SCN) bsum[t] = v - orig;   // exclusive
}

__global__ void scan_pass3(const int* __restrict__ deg, const int* __restrict__ boffs,
                           int* __restrict__ row_ptr, int* __restrict__ cursor) {
    int b = blockIdx.x, t = threadIdx.x;
    int base = b * SCB + t * 4;
    int d[4]; int tot = 0;
    #pragma unroll
    for (int i = 0; i < 4; i++) { int idx = base + i; d[i] = (idx < NN) ? deg[idx] : 0; tot += d[i]; }
    int v = tot;
    for (int off = 1; off < 64; off <<= 1) {
        int u = __shfl_up(v, off);
        if ((t & 63) >= off) v += u;
    }
    __shared__ int wsum[4];
    if ((t & 63) == 63) wsum[t >> 6] = v;
    __syncthreads();
    int woff = 0;
    for (int j = 0; j < (t >> 6); j++) woff += wsum[j];
    int run = boffs[b] + woff + v - tot;
    #pragma unroll
    for (int i = 0; i < 4; i++) {
        int idx = base + i;
        if (idx < NN) {
            cursor[idx] = run;
            run += d[i];
            row_ptr[idx + 1] = run;
        }
    }
    if (b == 0 && t == 0) row_ptr[0] = 0;
}

// fill CSR with materialized src / type / weight (no eid indirection later)
__global__ void fill_kernel(const int* __restrict__ ei, const int* __restrict__ etype,
                            const float* __restrict__ ew, int* __restrict__ cursor,
                            int* __restrict__ csr_src, int* __restrict__ csr_t,
                            float* __restrict__ csr_w) {
    int e = blockIdx.x * 256 + threadIdx.x;
    if (e >= EE) return;
    int dst = ei[EE + e];
    int pos = atomicAdd(&cursor[dst], 1);
    csr_src[pos] = ei[e];
    csr_t[pos]   = etype[e];
    csr_w[pos]   = ew[e];
}

// ---------------------------------------------------------------------------
// h_new[d] = h[d] + sum_{e: dst=d} (h[src_e] + rel_emb[type_e]*w_e)
// 4-deep chunked load pipelining; rel contribution deferred via per-type wsum.
__global__ void relagg_kernel(const float* __restrict__ h, const int* __restrict__ row_ptr,
                              const int* __restrict__ csr_src, const int* __restrict__ csr_t,
                              const float* __restrict__ csr_w,
                              const float* __restrict__ rel_emb, float* __restrict__ out)
{
    int lane = threadIdx.x & 63, wid = threadIdx.x >> 6;
    int node = blockIdx.x * 4 + wid;
    if (node >= NN) return;
    const float* hr = h + (size_t)node * HID;
    float acc[4];
    #pragma unroll
    for (int c = 0; c < 4; c++) acc[c] = hr[c * 64 + lane];
    float wsum[5] = {0.f, 0.f, 0.f, 0.f, 0.f};
    int beg = row_ptr[node], end = row_ptr[node + 1];
    int k = beg;
    for (; k + 4 <= end; k += 4) {
        int s[4], tt[4]; float ww[4];
        #pragma unroll
        for (int j = 0; j < 4; j++) {
            s[j]  = csr_src[k + j];
            tt[j] = csr_t[k + j];
            ww[j] = csr_w[k + j];
        }
        float xv[4][4];
        #pragma unroll
        for (int j = 0; j < 4; j++) {
            const float* hs = h + (size_t)s[j] * HID;
            #pragma unroll
            for (int c = 0; c < 4; c++) xv[j][c] = hs[c * 64 + lane];
        }
        #pragma unroll
        for (int j = 0; j < 4; j++) {
            #pragma unroll
            for (int c = 0; c < 4; c++) acc[c] += xv[j][c];
            #pragma unroll
            for (int r = 0; r < 5; r++) wsum[r] += (tt[j] == r) ? ww[j] : 0.f;
        }
    }
    for (; k < end; k++) {
        int src = csr_src[k]; int t = csr_t[k]; float w = csr_w[k];
        const float* hs = h + (size_t)src * HID;
        #pragma unroll
        for (int c = 0; c < 4; c++) acc[c] += hs[c * 64 + lane];
        #pragma unroll
        for (int r = 0; r < 5; r++) wsum[r] += (t == r) ? w : 0.f;
    }
    #pragma unroll
    for (int r = 0; r < 5; r++)
        #pragma unroll
        for (int c = 0; c < 4; c++) acc[c] += wsum[r] * rel_emb[r * HID + c * 64 + lane];
    float* o = out + (size_t)node * HID;
    #pragma unroll
    for (int c = 0; c < 4; c++) o[c * 64 + lane] = acc[c];
}

// GAT aggregation (online softmax, branchless, 4-deep chunked loads)
// + bias + residual + LayerNorm (+ optional final projection)
template<int FINAL>
__global__ void gat_kernel(const float* __restrict__ xh, const float* __restrict__ al_s,
                           const float* __restrict__ al_d, const int* __restrict__ row_ptr,
                           const int* __restrict__ csr_src, const float* __restrict__ h_res,
                           const float* __restrict__ bias, const float* __restrict__ ln_g,
                           const float* __restrict__ ln_b, float* __restrict__ out,
                           const float* __restrict__ W_out, const float* __restrict__ b_out,
                           float* __restrict__ final_out)
{
    int lane = threadIdx.x & 63, wid = threadIdx.x >> 6;
    int node = blockIdx.x * 4 + wid;
    if (node >= NN) return;

    float4 aldv = *(const float4*)&al_d[node * 4];
    float ald[4] = {aldv.x, aldv.y, aldv.z, aldv.w};
    float m[4], den[4], acc[4];

    // self-loop first (initializes the online state)
    {
        float4 alsv = *(const float4*)&al_s[node * 4];
        float als[4] = {alsv.x, alsv.y, alsv.z, alsv.w};
        const float* xs = xh + (size_t)node * HID;
        #pragma unroll
        for (int hh = 0; hh < 4; hh++) {
            float e = als[hh] + ald[hh];
            e = (e >= 0.f) ? e : 0.2f * e;
            m[hh] = e; den[hh] = 1.f;
            acc[hh] = xs[hh * 64 + lane];
        }
    }

    int beg = row_ptr[node], end = row_ptr[node + 1];
    int k = beg;
    for (; k + 4 <= end; k += 4) {
        int s[4];
        #pragma unroll
        for (int j = 0; j < 4; j++) s[j] = csr_src[k + j];
        float4 av[4];
        #pragma unroll
        for (int j = 0; j < 4; j++) av[j] = *(const float4*)&al_s[s[j] * 4];
        float xv[4][4];
        #pragma unroll
        for (int j = 0; j < 4; j++) {
            const float* xs = xh + (size_t)s[j] * HID;
            #pragma unroll
            for (int hh = 0; hh < 4; hh++) xv[j][hh] = xs[hh * 64 + lane];
        }
        #pragma unroll
        for (int j = 0; j < 4; j++) {
            float als[4] = {av[j].x, av[j].y, av[j].z, av[j].w};
            #pragma unroll
            for (int hh = 0; hh < 4; hh++) {
                float e = als[hh] + ald[hh];
                e = (e >= 0.f) ? e : 0.2f * e;
                float mn  = fmaxf(m[hh], e);
                float f   = __expf(m[hh] - mn);   // ==1 exactly when e<=m
                float wgt = __expf(e - mn);
                m[hh]   = mn;
                den[hh] = den[hh] * f + wgt;
                acc[hh] = acc[hh] * f + wgt * xv[j][hh];
            }
        }
    }
    for (; k < end; k++) {
        int src = csr_src[k];
        float4 alsv = *(const float4*)&al_s[src * 4];
        float als[4] = {alsv.x, alsv.y, alsv.z, alsv.w};
        const float* xs = xh + (size_t)src * HID;
        #pragma unroll
        for (int hh = 0; hh < 4; hh++) {
            float e = als[hh] + ald[hh];
            e = (e >= 0.f) ? e : 0.2f * e;
            float mn  = fmaxf(m[hh], e);
            float f   = __expf(m[hh] - mn);
            float wgt = __expf(e - mn);
            m[hh]   = mn;
            den[hh] = den[hh] * f + wgt;
            acc[hh] = acc[hh] * f + wgt * xs[hh * 64 + lane];
        }
    }

    float z[4];
    #pragma unroll
    for (int hh = 0; hh < 4; hh++) {
        int c = hh * 64 + lane;
        z[hh] = acc[hh] / (den[hh] + 1e-16f) + bias[c] + h_res[(size_t)node * HID + c];
    }
    float s = z[0] + z[1] + z[2] + z[3];
    #pragma unroll
    for (int off = 32; off; off >>= 1) s += __shfl_xor(s, off);
    float mean = s * (1.f / 256.f);
    float vp = 0.f;
    #pragma unroll
    for (int hh = 0; hh < 4; hh++) { float d2 = z[hh] - mean; vp += d2 * d2; }
    #pragma unroll
    for (int off = 32; off; off >>= 1) vp += __shfl_xor(vp, off);
    float rstd = rsqrtf(vp * (1.f / 256.f) + 1e-5f);

    if (FINAL) {
        float dot = 0.f;
        #pragma unroll
        for (int hh = 0; hh < 4; hh++) {
            int c = hh * 64 + lane;
            float v = (z[hh] - mean) * rstd * ln_g[c] + ln_b[c];
            dot += v * W_out[c];
        }
        #pragma unroll
        for (int off = 32; off; off >>= 1) dot += __shfl_xor(dot, off);
        if (lane == 0) final_out[node] = dot + b_out[0];
    } else {
        #pragma unroll
        for (int hh = 0; hh < 4; hh++) {
            int c = hh * 64 + lane;
            out[(size_t)node * HID + c] = (z[hh] - mean) * rstd * ln_g[c] + ln_b[c];
        }
    }
}

// ---------------------------------------------------------------------------
extern "C" void kernel_launch(void* const* d_in, const int* in_sizes, int n_in,
                              void* d_out, int out_size, void* d_ws, size_t ws_size,
                              hipStream_t stream) {
    const float* x       = (const float*)d_in[0];
    const int*   ei      = (const int*)d_in[1];
    const int*   etype   = (const int*)d_in[2];
    const float* ew      = (const float*)d_in[3];
    const float* rel_emb = (const float*)d_in[4];
    const float* W_in    = (const float*)d_in[5];
    const float* b_in    = (const float*)d_in[6];
    const float* W1      = (const float*)d_in[7];
    const float* a1s     = (const float*)d_in[8];
    const float* a1d     = (const float*)d_in[9];
    const float* b1      = (const float*)d_in[10];
    const float* W2      = (const float*)d_in[11];
    const float* a2s     = (const float*)d_in[12];
    const float* a2d     = (const float*)d_in[13];
    const float* b2      = (const float*)d_in[14];
    const float* ln1g    = (const float*)d_in[15];
    const float* ln1b    = (const float*)d_in[16];
    const float* ln2g    = (const float*)d_in[17];
    const float* ln2b    = (const float*)d_in[18];
    const float* W_out   = (const float*)d_in[19];
    const float* b_out   = (const float*)d_in[20];
    float* out = (float*)d_out;

    char* ws = (char*)d_ws;
    auto alloc = [&](size_t bytes) {
        void* p = (void*)ws;
        ws += (bytes + 255) & ~(size_t)255;
        return p;
    };
    float*  bufA     = (float*)alloc((size_t)NN * HID * 4);
    float*  bufB     = (float*)alloc((size_t)NN * HID * 4);
    float*  bufC     = (float*)alloc((size_t)NN * HID * 4);
    bf16_t* wmh      = (bf16_t*)alloc((size_t)HID * IND * 2);
    bf16_t* wml      = (bf16_t*)alloc((size_t)HID * IND * 2);
    bf16_t* w1h      = (bf16_t*)alloc((size_t)HID * HID * 2);
    bf16_t* w1l      = (bf16_t*)alloc((size_t)HID * HID * 2);
    bf16_t* w2h      = (bf16_t*)alloc((size_t)HID * HID * 2);
    bf16_t* w2l      = (bf16_t*)alloc((size_t)HID * HID * 2);
    float*  cbv      = (float*)alloc(256 * 4);
    float*  stats_s  = (float*)alloc(512 * 4);
    float*  stats_mi = (float*)alloc(512 * 4);
    float*  al_s     = (float*)alloc((size_t)NN * 4 * 4);
    float*  al_d     = (float*)alloc((size_t)NN * 4 * 4);
    int*    deg      = (int*)alloc((size_t)NN * 4);
    int*    row_ptr  = (int*)alloc((size_t)(NN + 1) * 4);
    int*    cursor   = (int*)alloc((size_t)NN * 4);
    int*    csr_src  = (int*)alloc((size_t)EE * 4);
    int*    csr_t    = (int*)alloc((size_t)EE * 4);
    float*  csr_w    = (float*)alloc((size_t)EE * 4);
    int*    bsum     = (int*)alloc(64 * 4);

    hipMemsetAsync(stats_s, 0, 512 * 4, stream);
    hipMemsetAsync(deg, 0, (size_t)NN * 4, stream);

    // input feature prep (row-norm computed inside the big GEMM)
    colstats_kernel<<<1024, 256, 0, stream>>>(x, stats_s);
    finalize_stats_kernel<<<1, 256, 0, stream>>>(stats_s, stats_mi);
    prep_w_kernel<<<256, 256, 0, stream>>>(W_in, stats_mi, b_in, wmh, wml, cbv);
    prep_ws_kernel<<<256, 256, 0, stream>>>(W1, w1h, w1l);
    prep_ws_kernel<<<256, 256, 0, stream>>>(W2, w2h, w2l);

    // CSR build
    deg_kernel<<<(EE + 255) / 256, 256, 0, stream>>>(ei, deg);
    scan_pass1<<<SCN, 256, 0, stream>>>(deg, bsum);
    scan_pass2<<<1, 64, 0, stream>>>(bsum);
    scan_pass3<<<SCN, 256, 0, stream>>>(deg, bsum, row_ptr, cursor);
    fill_kernel<<<(EE + 255) / 256, 256, 0, stream>>>(ei, etype, ew, cursor,
                                                      csr_src, csr_t, csr_w);

    dim3 g1((NN + 127) / 128, 2);

    // h0 = relu(xin @ W_in^T + b_in)  -> bufA
    gemm_mfma_kernel<1, 1024, 0><<<g1, 256, 0, stream>>>(
        x, wmh, wml, cbv, nullptr, nullptr, bufA, nullptr, nullptr);

    int nodeBlocks = (NN + 3) / 4;

    // relational aggregation -> bufB
    relagg_kernel<<<nodeBlocks, 256, 0, stream>>>(bufA, row_ptr, csr_src, csr_t, csr_w,
                                                  rel_emb, bufB);

    // ---- GAT layer 1 (xh GEMM with fused attention logits) ----
    gemm_mfma_kernel<0, 256, 1><<<g1, 256, 0, stream>>>(
        bufB, w1h, w1l, nullptr, a1s, a1d, bufC, al_s, al_d);
    gat_kernel<0><<<nodeBlocks, 256, 0, stream>>>(bufC, al_s, al_d, row_ptr, csr_src,
                                                  bufB, b1, ln1g, ln1b, bufA,
                                                  nullptr, nullptr, nullptr);

    // ---- GAT layer 2 (final projection fused) ----
    gemm_mfma_kernel<0, 256, 1><<<g1, 256, 0, stream>>>(
        bufA, w2h, w2l, nullptr, a2s, a2d, bufC, al_s, al_d);
    gat_kernel<1><<<nodeBlocks, 256, 0, stream>>>(bufC, al_s, al_d, row_ptr, csr_src,
                                                  bufA, b2, ln2g, ln2b, nullptr,
                                                  W_out, b_out, out);
}

// Round 8
// 495.761 us; speedup vs baseline: 1.0151x; 1.0151x over previous
//
#include <hip/hip_runtime.h>
#include <math.h>

// Problem constants (from reference)
constexpr int NN   = 50000;   // nodes
constexpr int EE   = 300000;  // edges
constexpr int IND  = 1024;    // IN_DIM
constexpr int CODE = 768;     // CODE_DIM
constexpr int HID  = 256;

typedef __bf16 bf16_t;
typedef bf16_t bf16x8 __attribute__((ext_vector_type(8)));
typedef float  f32x4  __attribute__((ext_vector_type(4)));

__device__ __forceinline__ f32x4 mfma16(bf16x8 a, bf16x8 b, f32x4 c) {
    return __builtin_amdgcn_mfma_f32_16x16x32_bf16(a, b, c, 0, 0, 0);
}

// async global->LDS, 16B per lane, wave-uniform LDS base + lane*16
#define GLOAD_LDS16(gp, lp) __builtin_amdgcn_global_load_lds(                         \
    (__attribute__((address_space(1))) void*)(gp),                                    \
    (__attribute__((address_space(3))) void*)(lp), 16, 0, 0)

// convert 8 fp32 -> hi/lo bf16 split (v = hi + lo, |lo| ~ 2^-8 |v|)
__device__ __forceinline__ void cvt_split(f32x4 u0, f32x4 u1, bf16x8& hi, bf16x8& lo) {
    #pragma unroll
    for (int i = 0; i < 4; i++) {
        bf16_t h0 = (bf16_t)u0[i];
        hi[i]     = h0;
        lo[i]     = (bf16_t)(u0[i] - (float)h0);
        bf16_t h1 = (bf16_t)u1[i];
        hi[4 + i] = h1;
        lo[4 + i] = (bf16_t)(u1[i] - (float)h1);
    }
}

// ---------------------------------------------------------------------------
// Stage 1: per-column sum/sumsq of x[:, 768:1024]
__global__ void colstats_kernel(const float* __restrict__ x, float* __restrict__ sums) {
    int col = threadIdx.x;             // 0..255
    float s = 0.f, s2 = 0.f;
    for (int row = blockIdx.x; row < NN; row += gridDim.x) {
        float v = x[(size_t)row * IND + CODE + col];
        s += v; s2 += v * v;
    }
    atomicAdd(&sums[col], s);
    atomicAdd(&sums[256 + col], s2);
}

__global__ void finalize_stats_kernel(const float* __restrict__ sums, float* __restrict__ mi) {
    int c = threadIdx.x;
    float mean = sums[c] / (float)NN;
    float var  = (sums[256 + c] - (float)NN * mean * mean) / (float)(NN - 1);
    float sd   = sqrtf(fmaxf(var, 0.f));
    sd = fmaxf(sd, 1e-6f);
    mi[c]       = mean;
    mi[256 + c] = 1.f / sd;
}

// Stage 2: per-row inverse L2 norm of x[:, 0:768]
__global__ void rownorm_kernel(const float* __restrict__ x, float* __restrict__ invnorm) {
    int lane = threadIdx.x & 63;
    int wid  = threadIdx.x >> 6;
    int row  = blockIdx.x * 4 + wid;
    if (row >= NN) return;
    const float4* x4 = (const float4*)(x + (size_t)row * IND);
    float s = 0.f;
    #pragma unroll
    for (int i = 0; i < 3; i++) {
        float4 v = x4[lane + i * 64];
        s += v.x * v.x + v.y * v.y + v.z * v.z + v.w * v.w;
    }
    #pragma unroll
    for (int off = 32; off; off >>= 1) s += __shfl_xor(s, off);
    if (lane == 0) invnorm[row] = 1.f / fmaxf(sqrtf(s), 1e-12f);
}

// Build Wmod (GEMM-ordered, numeric part pre-scaled) pre-split to bf16 hi/lo,
// and cb = b - d.
__global__ void prep_w_kernel(const float* __restrict__ W, const float* __restrict__ stats,
                              const float* __restrict__ b_in, bf16_t* __restrict__ Wh,
                              bf16_t* __restrict__ Wl, float* __restrict__ cb)
{
    int c = blockIdx.x, t = threadIdx.x;      // 256 blocks x 256 threads
    const float* wr = W + (size_t)c * IND;
    bf16_t* wh = Wh + (size_t)c * IND;
    bf16_t* wl = Wl + (size_t)c * IND;
    for (int k = t; k < 768; k += 256) {
        float v = wr[256 + k];
        bf16_t h = (bf16_t)v;
        wh[k] = h; wl[k] = (bf16_t)(v - (float)h);
    }
    {
        float v = wr[t] * stats[256 + t];
        bf16_t h = (bf16_t)v;
        wh[768 + t] = h; wl[768 + t] = (bf16_t)(v - (float)h);
    }
    float p = wr[t] * stats[256 + t] * stats[t];
    #pragma unroll
    for (int off = 32; off; off >>= 1) p += __shfl_xor(p, off);
    __shared__ float ps[4];
    if ((t & 63) == 0) ps[t >> 6] = p;
    __syncthreads();
    if (t == 0) cb[c] = b_in[c] - (ps[0] + ps[1] + ps[2] + ps[3]);
}

// small weights (256x256) -> bf16 hi/lo
__global__ void prep_ws_kernel(const float* __restrict__ W, bf16_t* __restrict__ Wh,
                               bf16_t* __restrict__ Wl)
{
    int c = blockIdx.x, t = threadIdx.x;
    float v = W[(size_t)c * 256 + t];
    bf16_t h = (bf16_t)v;
    Wh[(size_t)c * 256 + t] = h;
    Wl[(size_t)c * 256 + t] = (bf16_t)(v - (float)h);
}

// ---------------------------------------------------------------------------
// MFMA GEMM, split-bf16 (3 MFMAs), global_load_lds staging, double-buffered.
// MODE 1: A = x, B = Wmod; acc *= invnorm[row] at tile 24; epilogue
//         relu(acc+cb), fp32 out.
// FATTN 1: epilogue computes attention logits al_s/al_d (wave == one head)
//          and writes xh as bf16 (gather table for gat_kernel) - no fp32 out.
// Tile 128x128, BK=32, 256 threads = 4 waves (2x2), 64x64 per wave.

__device__ __forceinline__ void stage_a(const float* __restrict__ src, int ldk,
                                        int rowbase, int maxrow, int k0,
                                        float* ldsbuf, int tid) {
    int w = tid >> 6, l = tid & 63;
    int lr = l >> 3, lc = l & 7;
    int g  = lc ^ lr;                      // swizzled source chunk (row&7 == lr)
    #pragma unroll
    for (int i = 0; i < 4; i++) {
        int rloc = i * 32 + w * 8;
        float* dst = ldsbuf + rloc * 32;   // wave-uniform base
        int row = rowbase + rloc + lr;
        if (row > maxrow) row = maxrow;
        const float* gp = src + (size_t)row * ldk + k0 + g * 4;
        GLOAD_LDS16(gp, dst);
    }
}

// stage 128x32 bf16 tile; LDS slot p of col holds global chunk p^((col>>1)&3)
__device__ __forceinline__ void stage_b(const bf16_t* __restrict__ src, int n0, int ldk,
                                        int k0, bf16_t* buf, int tid) {
    int w = tid >> 6, l = tid & 63;
    #pragma unroll
    for (int i = 0; i < 2; i++) {
        int gbase = w * 128 + i * 64;
        bf16_t* dst = buf + gbase * 8;     // wave-uniform base (granule*8 bf16)
        int g = gbase + l;
        int col = g >> 2, p = g & 3;
        int gs = p ^ ((col >> 1) & 3);
        const bf16_t* gp = src + (size_t)(n0 + col) * ldk + k0 + gs * 8;
        GLOAD_LDS16(gp, dst);
    }
}

template<int MODE, int K, int FATTN>
__global__ __launch_bounds__(256) void gemm_mfma_kernel(
    const float* __restrict__ A, const bf16_t* __restrict__ Bh,
    const bf16_t* __restrict__ Bl, const float* __restrict__ cb,
    const float* __restrict__ invnorm, const float* __restrict__ a_src,
    const float* __restrict__ a_dst, float* __restrict__ out,
    bf16_t* __restrict__ xhb, float* __restrict__ al_s, float* __restrict__ al_d)
{
    __shared__ float  As[2][128 * 32];     // 32 KB
    __shared__ bf16_t Bhs[2][128 * 32];    // 16 KB
    __shared__ bf16_t Bls[2][128 * 32];    // 16 KB
    __shared__ float inv_s[128];
    constexpr int NT = K / 32;

    int tid  = threadIdx.x;
    int lane = tid & 63;
    int w    = tid >> 6;
    int wr   = w >> 1, wc = w & 1;
    int r0   = blockIdx.x * 128, n0 = blockIdx.y * 128;

    if (MODE == 1 && tid < 128) {
        int r = r0 + tid;
        inv_s[tid] = (r < NN) ? invnorm[r] : 1.f;
    }

    f32x4 acc[4][4];
    #pragma unroll
    for (int i = 0; i < 4; i++)
        #pragma unroll
        for (int j = 0; j < 4; j++) acc[i][j] = (f32x4)0.f;

    int kc = lane >> 4, fr = lane & 15;    // kc doubles as fq in epilogue

    stage_a(A, K, r0, NN - 1, 0, As[0], tid);
    stage_b(Bh, n0, K, 0, Bhs[0], tid);
    stage_b(Bl, n0, K, 0, Bls[0], tid);
    __syncthreads();   // vmcnt(0) drain: tile 0 resident

    for (int t = 0; t < NT; ++t) {
        int buf = t & 1;
        if (t + 1 < NT) {   // issue next tile; lands during this compute phase
            stage_a(A, K, r0, NN - 1, (t + 1) * 32, As[buf ^ 1], tid);
            stage_b(Bh, n0, K, (t + 1) * 32, Bhs[buf ^ 1], tid);
            stage_b(Bl, n0, K, (t + 1) * 32, Bls[buf ^ 1], tid);
        }
        if (MODE == 1 && t == 24) {  // kap==768: close code segment, scale by row norm
            #pragma unroll
            for (int mf = 0; mf < 4; mf++) {
                f32x4 iv = *(const f32x4*)&inv_s[wr * 64 + mf * 16 + kc * 4];
                #pragma unroll
                for (int nf = 0; nf < 4; nf++)
                    #pragma unroll
                    for (int j = 0; j < 4; j++) acc[mf][nf][j] *= iv[j];
            }
        }
        // ---- fragments + MFMA ----
        const float*  Ab = As[buf];
        const bf16_t* Hb = Bhs[buf];
        const bf16_t* Lb = Bls[buf];
        bf16x8 ahi[4], alo[4];
        #pragma unroll
        for (int mf = 0; mf < 4; mf++) {
            int r  = wr * 64 + mf * 16 + fr;
            int rb = r * 32, r7 = r & 7;
            f32x4 u0 = *(const f32x4*)&Ab[rb + (((2 * kc + 0) ^ r7) << 2)];
            f32x4 u1 = *(const f32x4*)&Ab[rb + (((2 * kc + 1) ^ r7) << 2)];
            cvt_split(u0, u1, ahi[mf], alo[mf]);
        }
        #pragma unroll
        for (int nf = 0; nf < 4; nf++) {
            int c  = wc * 64 + nf * 16 + fr;
            int pr = kc ^ ((c >> 1) & 3);
            bf16x8 bhi = *(const bf16x8*)&Hb[c * 32 + pr * 8];
            bf16x8 blo = *(const bf16x8*)&Lb[c * 32 + pr * 8];
            #pragma unroll
            for (int mf = 0; mf < 4; mf++) {
                acc[mf][nf] = mfma16(ahi[mf], bhi, acc[mf][nf]);
                acc[mf][nf] = mfma16(alo[mf], bhi, acc[mf][nf]);
                acc[mf][nf] = mfma16(ahi[mf], blo, acc[mf][nf]);
            }
        }
        __syncthreads();  // tile t+1 landed; all reads of buf done
    }

    // ---- epilogue ----
    int head = blockIdx.y * 2 + wc;
    float asv[4], adv[4];
    if (FATTN) {
        #pragma unroll
        for (int nf = 0; nf < 4; nf++) {
            asv[nf] = a_src[head * 64 + nf * 16 + fr];
            adv[nf] = a_dst[head * 64 + nf * 16 + fr];
        }
    }
    #pragma unroll
    for (int mf = 0; mf < 4; mf++) {
        #pragma unroll
        for (int j = 0; j < 4; j++) {
            int row = r0 + wr * 64 + mf * 16 + kc * 4 + j;
            bool ok = row < NN;
            float s = 0.f, d = 0.f;
            #pragma unroll
            for (int nf = 0; nf < 4; nf++) {
                int col = n0 + wc * 64 + nf * 16 + fr;
                float v = acc[mf][nf][j];
                if (MODE == 1) {
                    v = fmaxf(v + cb[col], 0.f);
                    if (ok) out[(size_t)row * HID + col] = v;
                }
                if (FATTN) {
                    s += v * asv[nf]; d += v * adv[nf];
                    if (ok) xhb[(size_t)row * HID + col] = (bf16_t)v;  // bf16 gather table
                }
            }
            if (FATTN) {
                #pragma unroll
                for (int off = 1; off < 16; off <<= 1) {
                    s += __shfl_xor(s, off);
                    d += __shfl_xor(d, off);
                }
                if (ok && fr == 0) {
                    al_s[row * 4 + head] = s;
                    al_d[row * 4 + head] = d;
                }
            }
        }
    }
}

// ---------------------------------------------------------------------------
// CSR build (by destination)
__global__ void deg_kernel(const int* __restrict__ ei, int* __restrict__ deg) {
    int e = blockIdx.x * 256 + threadIdx.x;
    if (e < EE) atomicAdd(&deg[ei[EE + e]], 1);
}

constexpr int SCB = 1024;                       // elems per scan block
constexpr int SCN = (NN + SCB - 1) / SCB;       // 49

__global__ void scan_pass1(const int* __restrict__ deg, int* __restrict__ bsum) {
    int b = blockIdx.x, t = threadIdx.x;
    int base = b * SCB + t * 4;
    int s = 0;
    #pragma unroll
    for (int i = 0; i < 4; i++) { int idx = base + i; if (idx < NN) s += deg[idx]; }
    #pragma unroll
    for (int off = 32; off; off >>= 1) s += __shfl_xor(s, off);
    __shared__ int ps[4];
    if ((t & 63) == 0) ps[t >> 6] = s;
    __syncthreads();
    if (t == 0) bsum[b] = ps[0] + ps[1] + ps[2] + ps[3];
}

__global__ void scan_pass2(int* __restrict__ bsum) {   // 1 block, 64 threads
    int t = threadIdx.x;
    int orig = (t < SCN) ? bsum[t] : 0;
    int v = orig;
    for (int off = 1; off < 64; off <<= 1) {
        int u = __shfl_up(v, off);
        if (t >= off) v += u;
    }
    if (t < SCN) bsum[t] = v - orig;   // exclusive
}

__global__ void scan_pass3(const int* __restrict__ deg, const int* __restrict__ boffs,
                           int* __restrict__ row_ptr, int* __restrict__ cursor) {
    int b = blockIdx.x, t = threadIdx.x;
    int base = b * SCB + t * 4;
    int d[4]; int tot = 0;
    #pragma unroll
    for (int i = 0; i < 4; i++) { int idx = base + i; d[i] = (idx < NN) ? deg[idx] : 0; tot += d[i]; }
    int v = tot;
    for (int off = 1; off < 64; off <<= 1) {
        int u = __shfl_up(v, off);
        if ((t & 63) >= off) v += u;
    }
    __shared__ int wsum[4];
    if ((t & 63) == 63) wsum[t >> 6] = v;
    __syncthreads();
    int woff = 0;
    for (int j = 0; j < (t >> 6); j++) woff += wsum[j];
    int run = boffs[b] + woff + v - tot;
    #pragma unroll
    for (int i = 0; i < 4; i++) {
        int idx = base + i;
        if (idx < NN) {
            cursor[idx] = run;
            run += d[i];
            row_ptr[idx + 1] = run;
        }
    }
    if (b == 0 && t == 0) row_ptr[0] = 0;
}

// fill CSR with materialized src / type / weight (no eid indirection later)
__global__ void fill_kernel(const int* __restrict__ ei, const int* __restrict__ etype,
                            const float* __restrict__ ew, int* __restrict__ cursor,
                            int* __restrict__ csr_src, int* __restrict__ csr_t,
                            float* __restrict__ csr_w) {
    int e = blockIdx.x * 256 + threadIdx.x;
    if (e >= EE) return;
    int dst = ei[EE + e];
    int pos = atomicAdd(&cursor[dst], 1);
    csr_src[pos] = ei[e];
    csr_t[pos]   = etype[e];
    csr_w[pos]   = ew[e];
}

// ---------------------------------------------------------------------------
// h_new[d] = h[d] + sum_{e: dst=d} (h[src_e] + rel_emb[type_e]*w_e)
// 4-deep chunked load pipelining; rel contribution deferred via per-type wsum.
__global__ void relagg_kernel(const float* __restrict__ h, const int* __restrict__ row_ptr,
                              const int* __restrict__ csr_src, const int* __restrict__ csr_t,
                              const float* __restrict__ csr_w,
                              const float* __restrict__ rel_emb, float* __restrict__ out)
{
    int lane = threadIdx.x & 63, wid = threadIdx.x >> 6;
    int node = blockIdx.x * 4 + wid;
    if (node >= NN) return;
    const float* hr = h + (size_t)node * HID;
    float acc[4];
    #pragma unroll
    for (int c = 0; c < 4; c++) acc[c] = hr[c * 64 + lane];
    float wsum[5] = {0.f, 0.f, 0.f, 0.f, 0.f};
    int beg = row_ptr[node], end = row_ptr[node + 1];
    int k = beg;
    for (; k + 4 <= end; k += 4) {
        int s[4], tt[4]; float ww[4];
        #pragma unroll
        for (int j = 0; j < 4; j++) {
            s[j]  = csr_src[k + j];
            tt[j] = csr_t[k + j];
            ww[j] = csr_w[k + j];
        }
        float xv[4][4];
        #pragma unroll
        for (int j = 0; j < 4; j++) {
            const float* hs = h + (size_t)s[j] * HID;
            #pragma unroll
            for (int c = 0; c < 4; c++) xv[j][c] = hs[c * 64 + lane];
        }
        #pragma unroll
        for (int j = 0; j < 4; j++) {
            #pragma unroll
            for (int c = 0; c < 4; c++) acc[c] += xv[j][c];
            #pragma unroll
            for (int r = 0; r < 5; r++) wsum[r] += (tt[j] == r) ? ww[j] : 0.f;
        }
    }
    for (; k < end; k++) {
        int src = csr_src[k]; int t = csr_t[k]; float w = csr_w[k];
        const float* hs = h + (size_t)src * HID;
        #pragma unroll
        for (int c = 0; c < 4; c++) acc[c] += hs[c * 64 + lane];
        #pragma unroll
        for (int r = 0; r < 5; r++) wsum[r] += (t == r) ? w : 0.f;
    }
    #pragma unroll
    for (int r = 0; r < 5; r++)
        #pragma unroll
        for (int c = 0; c < 4; c++) acc[c] += wsum[r] * rel_emb[r * HID + c * 64 + lane];
    float* o = out + (size_t)node * HID;
    #pragma unroll
    for (int c = 0; c < 4; c++) o[c * 64 + lane] = acc[c];
}

// GAT aggregation (online softmax, branchless, 4-deep chunked loads) over a
// bf16 xh gather table + bias + residual + LayerNorm (+ optional final proj)
template<int FINAL>
__global__ void gat_kernel(const bf16_t* __restrict__ xhb, const float* __restrict__ al_s,
                           const float* __restrict__ al_d, const int* __restrict__ row_ptr,
                           const int* __restrict__ csr_src, const float* __restrict__ h_res,
                           const float* __restrict__ bias, const float* __restrict__ ln_g,
                           const float* __restrict__ ln_b, float* __restrict__ out,
                           const float* __restrict__ W_out, const float* __restrict__ b_out,
                           float* __restrict__ final_out)
{
    int lane = threadIdx.x & 63, wid = threadIdx.x >> 6;
    int node = blockIdx.x * 4 + wid;
    if (node >= NN) return;

    float4 aldv = *(const float4*)&al_d[node * 4];
    float ald[4] = {aldv.x, aldv.y, aldv.z, aldv.w};
    float m[4], den[4], acc[4];

    // self-loop first (initializes the online state)
    {
        float4 alsv = *(const float4*)&al_s[node * 4];
        float als[4] = {alsv.x, alsv.y, alsv.z, alsv.w};
        const bf16_t* xs = xhb + (size_t)node * HID;
        #pragma unroll
        for (int hh = 0; hh < 4; hh++) {
            float e = als[hh] + ald[hh];
            e = (e >= 0.f) ? e : 0.2f * e;
            m[hh] = e; den[hh] = 1.f;
            acc[hh] = (float)xs[hh * 64 + lane];
        }
    }

    int beg = row_ptr[node], end = row_ptr[node + 1];
    int k = beg;
    for (; k + 4 <= end; k += 4) {
        int s[4];
        #pragma unroll
        for (int j = 0; j < 4; j++) s[j] = csr_src[k + j];
        float4 av[4];
        #pragma unroll
        for (int j = 0; j < 4; j++) av[j] = *(const float4*)&al_s[s[j] * 4];
        float xv[4][4];
        #pragma unroll
        for (int j = 0; j < 4; j++) {
            const bf16_t* xs = xhb + (size_t)s[j] * HID;
            #pragma unroll
            for (int hh = 0; hh < 4; hh++) xv[j][hh] = (float)xs[hh * 64 + lane];
        }
        #pragma unroll
        for (int j = 0; j < 4; j++) {
            float als[4] = {av[j].x, av[j].y, av[j].z, av[j].w};
            #pragma unroll
            for (int hh = 0; hh < 4; hh++) {
                float e = als[hh] + ald[hh];
                e = (e >= 0.f) ? e : 0.2f * e;
                float mn  = fmaxf(m[hh], e);
                float f   = __expf(m[hh] - mn);   // ==1 exactly when e<=m
                float wgt = __expf(e - mn);
                m[hh]   = mn;
                den[hh] = den[hh] * f + wgt;
                acc[hh] = acc[hh] * f + wgt * xv[j][hh];
            }
        }
    }
    for (; k < end; k++) {
        int src = csr_src[k];
        float4 alsv = *(const float4*)&al_s[src * 4];
        float als[4] = {alsv.x, alsv.y, alsv.z, alsv.w};
        const bf16_t* xs = xhb + (size_t)src * HID;
        #pragma unroll
        for (int hh = 0; hh < 4; hh++) {
            float e = als[hh] + ald[hh];
            e = (e >= 0.f) ? e : 0.2f * e;
            float mn  = fmaxf(m[hh], e);
            float f   = __expf(m[hh] - mn);
            float wgt = __expf(e - mn);
            m[hh]   = mn;
            den[hh] = den[hh] * f + wgt;
            acc[hh] = acc[hh] * f + wgt * (float)xs[hh * 64 + lane];
        }
    }

    float z[4];
    #pragma unroll
    for (int hh = 0; hh < 4; hh++) {
        int c = hh * 64 + lane;
        z[hh] = acc[hh] / (den[hh] + 1e-16f) + bias[c] + h_res[(size_t)node * HID + c];
    }
    float s = z[0] + z[1] + z[2] + z[3];
    #pragma unroll
    for (int off = 32; off; off >>= 1) s += __shfl_xor(s, off);
    float mean = s * (1.f / 256.f);
    float vp = 0.f;
    #pragma unroll
    for (int hh = 0; hh < 4; hh++) { float d2 = z[hh] - mean; vp += d2 * d2; }
    #pragma unroll
    for (int off = 32; off; off >>= 1) vp += __shfl_xor(vp, off);
    float rstd = rsqrtf(vp * (1.f / 256.f) + 1e-5f);

    if (FINAL) {
        float dot = 0.f;
        #pragma unroll
        for (int hh = 0; hh < 4; hh++) {
            int c = hh * 64 + lane;
            float v = (z[hh] - mean) * rstd * ln_g[c] + ln_b[c];
            dot += v * W_out[c];
        }
        #pragma unroll
        for (int off = 32; off; off >>= 1) dot += __shfl_xor(dot, off);
        if (lane == 0) final_out[node] = dot + b_out[0];
    } else {
        #pragma unroll
        for (int hh = 0; hh < 4; hh++) {
            int c = hh * 64 + lane;
            out[(size_t)node * HID + c] = (z[hh] - mean) * rstd * ln_g[c] + ln_b[c];
        }
    }
}

// ---------------------------------------------------------------------------
extern "C" void kernel_launch(void* const* d_in, const int* in_sizes, int n_in,
                              void* d_out, int out_size, void* d_ws, size_t ws_size,
                              hipStream_t stream) {
    const float* x       = (const float*)d_in[0];
    const int*   ei      = (const int*)d_in[1];
    const int*   etype   = (const int*)d_in[2];
    const float* ew      = (const float*)d_in[3];
    const float* rel_emb = (const float*)d_in[4];
    const float* W_in    = (const float*)d_in[5];
    const float* b_in    = (const float*)d_in[6];
    const float* W1      = (const float*)d_in[7];
    const float* a1s     = (const float*)d_in[8];
    const float* a1d     = (const float*)d_in[9];
    const float* b1      = (const float*)d_in[10];
    const float* W2      = (const float*)d_in[11];
    const float* a2s     = (const float*)d_in[12];
    const float* a2d     = (const float*)d_in[13];
    const float* b2      = (const float*)d_in[14];
    const float* ln1g    = (const float*)d_in[15];
    const float* ln1b    = (const float*)d_in[16];
    const float* ln2g    = (const float*)d_in[17];
    const float* ln2b    = (const float*)d_in[18];
    const float* W_out   = (const float*)d_in[19];
    const float* b_out   = (const float*)d_in[20];
    float* out = (float*)d_out;

    char* ws = (char*)d_ws;
    auto alloc = [&](size_t bytes) {
        void* p = (void*)ws;
        ws += (bytes + 255) & ~(size_t)255;
        return p;
    };
    float*  bufA     = (float*)alloc((size_t)NN * HID * 4);
    float*  bufB     = (float*)alloc((size_t)NN * HID * 4);
    bf16_t* xhb      = (bf16_t*)alloc((size_t)NN * HID * 2);
    bf16_t* wmh      = (bf16_t*)alloc((size_t)HID * IND * 2);
    bf16_t* wml      = (bf16_t*)alloc((size_t)HID * IND * 2);
    bf16_t* w1h      = (bf16_t*)alloc((size_t)HID * HID * 2);
    bf16_t* w1l      = (bf16_t*)alloc((size_t)HID * HID * 2);
    bf16_t* w2h      = (bf16_t*)alloc((size_t)HID * HID * 2);
    bf16_t* w2l      = (bf16_t*)alloc((size_t)HID * HID * 2);
    float*  cbv      = (float*)alloc(256 * 4);
    float*  stats_s  = (float*)alloc(512 * 4);
    float*  stats_mi = (float*)alloc(512 * 4);
    float*  invnorm  = (float*)alloc((size_t)NN * 4);
    float*  al_s     = (float*)alloc((size_t)NN * 4 * 4);
    float*  al_d     = (float*)alloc((size_t)NN * 4 * 4);
    int*    deg      = (int*)alloc((size_t)NN * 4);
    int*    row_ptr  = (int*)alloc((size_t)(NN + 1) * 4);
    int*    cursor   = (int*)alloc((size_t)NN * 4);
    int*    csr_src  = (int*)alloc((size_t)EE * 4);
    int*    csr_t    = (int*)alloc((size_t)EE * 4);
    float*  csr_w    = (float*)alloc((size_t)EE * 4);
    int*    bsum     = (int*)alloc(64 * 4);

    hipMemsetAsync(stats_s, 0, 512 * 4, stream);
    hipMemsetAsync(deg, 0, (size_t)NN * 4, stream);

    // input feature prep
    colstats_kernel<<<1024, 256, 0, stream>>>(x, stats_s);
    finalize_stats_kernel<<<1, 256, 0, stream>>>(stats_s, stats_mi);
    rownorm_kernel<<<(NN + 3) / 4, 256, 0, stream>>>(x, invnorm);
    prep_w_kernel<<<256, 256, 0, stream>>>(W_in, stats_mi, b_in, wmh, wml, cbv);
    prep_ws_kernel<<<256, 256, 0, stream>>>(W1, w1h, w1l);
    prep_ws_kernel<<<256, 256, 0, stream>>>(W2, w2h, w2l);

    // CSR build
    deg_kernel<<<(EE + 255) / 256, 256, 0, stream>>>(ei, deg);
    scan_pass1<<<SCN, 256, 0, stream>>>(deg, bsum);
    scan_pass2<<<1, 64, 0, stream>>>(bsum);
    scan_pass3<<<SCN, 256, 0, stream>>>(deg, bsum, row_ptr, cursor);
    fill_kernel<<<(EE + 255) / 256, 256, 0, stream>>>(ei, etype, ew, cursor,
                                                      csr_src, csr_t, csr_w);

    dim3 g1((NN + 127) / 128, 2);

    // h0 = relu(xin @ W_in^T + b_in)  -> bufA (fp32)
    gemm_mfma_kernel<1, 1024, 0><<<g1, 256, 0, stream>>>(
        x, wmh, wml, cbv, invnorm, nullptr, nullptr, bufA, nullptr, nullptr, nullptr);

    int nodeBlocks = (NN + 3) / 4;

    // relational aggregation -> bufB (fp32)
    relagg_kernel<<<nodeBlocks, 256, 0, stream>>>(bufA, row_ptr, csr_src, csr_t, csr_w,
                                                  rel_emb, bufB);

    // ---- GAT layer 1 (xh GEMM -> bf16 table + fused attention logits) ----
    gemm_mfma_kernel<0, 256, 1><<<g1, 256, 0, stream>>>(
        bufB, w1h, w1l, nullptr, nullptr, a1s, a1d, nullptr, xhb, al_s, al_d);
    gat_kernel<0><<<nodeBlocks, 256, 0, stream>>>(xhb, al_s, al_d, row_ptr, csr_src,
                                                  bufB, b1, ln1g, ln1b, bufA,
                                                  nullptr, nullptr, nullptr);

    // ---- GAT layer 2 (final projection fused) ----
    gemm_mfma_kernel<0, 256, 1><<<g1, 256, 0, stream>>>(
        bufA, w2h, w2l, nullptr, nullptr, a2s, a2d, nullptr, xhb, al_s, al_d);
    gat_kernel<1><<<nodeBlocks, 256, 0, stream>>>(xhb, al_s, al_d, row_ptr, csr_src,
                                                  bufA, b2, ln2g, ln2b, nullptr,
                                                  W_out, b_out, out);
}

// Round 9
// 445.264 us; speedup vs baseline: 1.1302x; 1.1134x over previous
//
#include <hip/hip_runtime.h>
#include <math.h>

// Problem constants (from reference)
constexpr int NN   = 50000;   // nodes
constexpr int EE   = 300000;  // edges
constexpr int IND  = 1024;    // IN_DIM
constexpr int CODE = 768;     // CODE_DIM
constexpr int HID  = 256;

typedef __bf16 bf16_t;
typedef bf16_t bf16x4 __attribute__((ext_vector_type(4)));
typedef bf16_t bf16x8 __attribute__((ext_vector_type(8)));
typedef float  f32x4  __attribute__((ext_vector_type(4)));

__device__ __forceinline__ f32x4 mfma16(bf16x8 a, bf16x8 b, f32x4 c) {
    return __builtin_amdgcn_mfma_f32_16x16x32_bf16(a, b, c, 0, 0, 0);
}

// async global->LDS, 16B per lane, wave-uniform LDS base + lane*16
#define GLOAD_LDS16(gp, lp) __builtin_amdgcn_global_load_lds(                         \
    (__attribute__((address_space(1))) void*)(gp),                                    \
    (__attribute__((address_space(3))) void*)(lp), 16, 0, 0)

// convert 8 fp32 -> hi/lo bf16 split (v = hi + lo, |lo| ~ 2^-8 |v|)
__device__ __forceinline__ void cvt_split(f32x4 u0, f32x4 u1, bf16x8& hi, bf16x8& lo) {
    #pragma unroll
    for (int i = 0; i < 4; i++) {
        bf16_t h0 = (bf16_t)u0[i];
        hi[i]     = h0;
        lo[i]     = (bf16_t)(u0[i] - (float)h0);
        bf16_t h1 = (bf16_t)u1[i];
        hi[4 + i] = h1;
        lo[4 + i] = (bf16_t)(u1[i] - (float)h1);
    }
}

// load 4 consecutive bf16 -> f32x4
__device__ __forceinline__ f32x4 ld_bf4(const bf16_t* p) {
    bf16x4 v = *(const bf16x4*)p;
    f32x4 r;
    r[0] = (float)v[0]; r[1] = (float)v[1]; r[2] = (float)v[2]; r[3] = (float)v[3];
    return r;
}

// ---------------------------------------------------------------------------
// Stage 1: per-column sum/sumsq of x[:, 768:1024]
__global__ void colstats_kernel(const float* __restrict__ x, float* __restrict__ sums) {
    int col = threadIdx.x;             // 0..255
    float s = 0.f, s2 = 0.f;
    for (int row = blockIdx.x; row < NN; row += gridDim.x) {
        float v = x[(size_t)row * IND + CODE + col];
        s += v; s2 += v * v;
    }
    atomicAdd(&sums[col], s);
    atomicAdd(&sums[256 + col], s2);
}

__global__ void finalize_stats_kernel(const float* __restrict__ sums, float* __restrict__ mi) {
    int c = threadIdx.x;
    float mean = sums[c] / (float)NN;
    float var  = (sums[256 + c] - (float)NN * mean * mean) / (float)(NN - 1);
    float sd   = sqrtf(fmaxf(var, 0.f));
    sd = fmaxf(sd, 1e-6f);
    mi[c]       = mean;
    mi[256 + c] = 1.f / sd;
}

// Stage 2: per-row inverse L2 norm of x[:, 0:768]
__global__ void rownorm_kernel(const float* __restrict__ x, float* __restrict__ invnorm) {
    int lane = threadIdx.x & 63;
    int wid  = threadIdx.x >> 6;
    int row  = blockIdx.x * 4 + wid;
    if (row >= NN) return;
    const float4* x4 = (const float4*)(x + (size_t)row * IND);
    float s = 0.f;
    #pragma unroll
    for (int i = 0; i < 3; i++) {
        float4 v = x4[lane + i * 64];
        s += v.x * v.x + v.y * v.y + v.z * v.z + v.w * v.w;
    }
    #pragma unroll
    for (int off = 32; off; off >>= 1) s += __shfl_xor(s, off);
    if (lane == 0) invnorm[row] = 1.f / fmaxf(sqrtf(s), 1e-12f);
}

// Build Wmod (GEMM-ordered, numeric part pre-scaled) pre-split to bf16 hi/lo,
// and cb = b - d.
__global__ void prep_w_kernel(const float* __restrict__ W, const float* __restrict__ stats,
                              const float* __restrict__ b_in, bf16_t* __restrict__ Wh,
                              bf16_t* __restrict__ Wl, float* __restrict__ cb)
{
    int c = blockIdx.x, t = threadIdx.x;      // 256 blocks x 256 threads
    const float* wr = W + (size_t)c * IND;
    bf16_t* wh = Wh + (size_t)c * IND;
    bf16_t* wl = Wl + (size_t)c * IND;
    for (int k = t; k < 768; k += 256) {
        float v = wr[256 + k];
        bf16_t h = (bf16_t)v;
        wh[k] = h; wl[k] = (bf16_t)(v - (float)h);
    }
    {
        float v = wr[t] * stats[256 + t];
        bf16_t h = (bf16_t)v;
        wh[768 + t] = h; wl[768 + t] = (bf16_t)(v - (float)h);
    }
    float p = wr[t] * stats[256 + t] * stats[t];
    #pragma unroll
    for (int off = 32; off; off >>= 1) p += __shfl_xor(p, off);
    __shared__ float ps[4];
    if ((t & 63) == 0) ps[t >> 6] = p;
    __syncthreads();
    if (t == 0) cb[c] = b_in[c] - (ps[0] + ps[1] + ps[2] + ps[3]);
}

// small weights (256x256) -> bf16 hi/lo
__global__ void prep_ws_kernel(const float* __restrict__ W, bf16_t* __restrict__ Wh,
                               bf16_t* __restrict__ Wl)
{
    int c = blockIdx.x, t = threadIdx.x;
    float v = W[(size_t)c * 256 + t];
    bf16_t h = (bf16_t)v;
    Wh[(size_t)c * 256 + t] = h;
    Wl[(size_t)c * 256 + t] = (bf16_t)(v - (float)h);
}

// ---------------------------------------------------------------------------
// MFMA GEMM, split-bf16, global_load_lds staging, double-buffered.
// MODE 1: A = x, B = Wmod; acc *= invnorm[row] at tile 24; epilogue
//         relu(acc+cb), fp32 out. 2-term split (no ahi*blo; B-lo dropped):
//         LDS 49.5 KB -> 3 blocks/CU.
// MODE 0 (+FATTN): 3-term split; epilogue computes attention logits
//         al_s/al_d (wave == one head) and writes xh as bf16.
// Tile 128x128, BK=32, 256 threads = 4 waves (2x2), 64x64 per wave.

__device__ __forceinline__ void stage_a(const float* __restrict__ src, int ldk,
                                        int rowbase, int maxrow, int k0,
                                        float* ldsbuf, int tid) {
    int w = tid >> 6, l = tid & 63;
    int lr = l >> 3, lc = l & 7;
    int g  = lc ^ lr;                      // swizzled source chunk (row&7 == lr)
    #pragma unroll
    for (int i = 0; i < 4; i++) {
        int rloc = i * 32 + w * 8;
        float* dst = ldsbuf + rloc * 32;   // wave-uniform base
        int row = rowbase + rloc + lr;
        if (row > maxrow) row = maxrow;
        const float* gp = src + (size_t)row * ldk + k0 + g * 4;
        GLOAD_LDS16(gp, dst);
    }
}

// stage 128x32 bf16 tile; LDS slot p of col holds global chunk p^((col>>1)&3)
__device__ __forceinline__ void stage_b(const bf16_t* __restrict__ src, int n0, int ldk,
                                        int k0, bf16_t* buf, int tid) {
    int w = tid >> 6, l = tid & 63;
    #pragma unroll
    for (int i = 0; i < 2; i++) {
        int gbase = w * 128 + i * 64;
        bf16_t* dst = buf + gbase * 8;     // wave-uniform base (granule*8 bf16)
        int g = gbase + l;
        int col = g >> 2, p = g & 3;
        int gs = p ^ ((col >> 1) & 3);
        const bf16_t* gp = src + (size_t)(n0 + col) * ldk + k0 + gs * 8;
        GLOAD_LDS16(gp, dst);
    }
}

template<int MODE, int K, int FATTN>
__global__ __launch_bounds__(256) void gemm_mfma_kernel(
    const float* __restrict__ A, const bf16_t* __restrict__ Bh,
    const bf16_t* __restrict__ Bl, const float* __restrict__ cb,
    const float* __restrict__ invnorm, const float* __restrict__ a_src,
    const float* __restrict__ a_dst, float* __restrict__ out,
    bf16_t* __restrict__ xhb, float* __restrict__ al_s, float* __restrict__ al_d)
{
    __shared__ float  As[2][128 * 32];                         // 32 KB
    __shared__ bf16_t Bhs[2][128 * 32];                        // 16 KB
    constexpr int BLN = (MODE == 1) ? 8 : 2 * 128 * 32;
    __shared__ bf16_t Bls[BLN];                                // 16 KB (MODE 0)
    __shared__ float inv_s[128];
    constexpr int NT = K / 32;

    int tid  = threadIdx.x;
    int lane = tid & 63;
    int w    = tid >> 6;
    int wr   = w >> 1, wc = w & 1;
    int r0   = blockIdx.x * 128, n0 = blockIdx.y * 128;

    if (MODE == 1 && tid < 128) {
        int r = r0 + tid;
        inv_s[tid] = (r < NN) ? invnorm[r] : 1.f;
    }

    f32x4 acc[4][4];
    #pragma unroll
    for (int i = 0; i < 4; i++)
        #pragma unroll
        for (int j = 0; j < 4; j++) acc[i][j] = (f32x4)0.f;

    int kc = lane >> 4, fr = lane & 15;    // kc doubles as fq in epilogue

    stage_a(A, K, r0, NN - 1, 0, As[0], tid);
    stage_b(Bh, n0, K, 0, Bhs[0], tid);
    if (MODE == 0) stage_b(Bl, n0, K, 0, Bls, tid);
    __syncthreads();   // vmcnt(0) drain: tile 0 resident

    for (int t = 0; t < NT; ++t) {
        int buf = t & 1;
        if (t + 1 < NT) {   // issue next tile; lands during this compute phase
            stage_a(A, K, r0, NN - 1, (t + 1) * 32, As[buf ^ 1], tid);
            stage_b(Bh, n0, K, (t + 1) * 32, Bhs[buf ^ 1], tid);
            if (MODE == 0) stage_b(Bl, n0, K, (t + 1) * 32, Bls + (buf ^ 1) * (128 * 32), tid);
        }
        if (MODE == 1 && t == 24) {  // kap==768: close code segment, scale by row norm
            #pragma unroll
            for (int mf = 0; mf < 4; mf++) {
                f32x4 iv = *(const f32x4*)&inv_s[wr * 64 + mf * 16 + kc * 4];
                #pragma unroll
                for (int nf = 0; nf < 4; nf++)
                    #pragma unroll
                    for (int j = 0; j < 4; j++) acc[mf][nf][j] *= iv[j];
            }
        }
        // ---- fragments + MFMA ----
        const float*  Ab = As[buf];
        const bf16_t* Hb = Bhs[buf];
        const bf16_t* Lb = Bls + buf * (128 * 32);
        bf16x8 ahi[4], alo[4];
        #pragma unroll
        for (int mf = 0; mf < 4; mf++) {
            int r  = wr * 64 + mf * 16 + fr;
            int rb = r * 32, r7 = r & 7;
            f32x4 u0 = *(const f32x4*)&Ab[rb + (((2 * kc + 0) ^ r7) << 2)];
            f32x4 u1 = *(const f32x4*)&Ab[rb + (((2 * kc + 1) ^ r7) << 2)];
            cvt_split(u0, u1, ahi[mf], alo[mf]);
        }
        #pragma unroll
        for (int nf = 0; nf < 4; nf++) {
            int c  = wc * 64 + nf * 16 + fr;
            int pr = kc ^ ((c >> 1) & 3);
            bf16x8 bhi = *(const bf16x8*)&Hb[c * 32 + pr * 8];
            #pragma unroll
            for (int mf = 0; mf < 4; mf++) {
                acc[mf][nf] = mfma16(ahi[mf], bhi, acc[mf][nf]);
                acc[mf][nf] = mfma16(alo[mf], bhi, acc[mf][nf]);
            }
            if (MODE == 0) {
                bf16x8 blo = *(const bf16x8*)&Lb[c * 32 + pr * 8];
                #pragma unroll
                for (int mf = 0; mf < 4; mf++)
                    acc[mf][nf] = mfma16(ahi[mf], blo, acc[mf][nf]);
            }
        }
        __syncthreads();  // tile t+1 landed; all reads of buf done
    }

    // ---- epilogue ----
    int head = blockIdx.y * 2 + wc;
    float asv[4], adv[4];
    if (FATTN) {
        #pragma unroll
        for (int nf = 0; nf < 4; nf++) {
            asv[nf] = a_src[head * 64 + nf * 16 + fr];
            adv[nf] = a_dst[head * 64 + nf * 16 + fr];
        }
    }
    #pragma unroll
    for (int mf = 0; mf < 4; mf++) {
        #pragma unroll
        for (int j = 0; j < 4; j++) {
            int row = r0 + wr * 64 + mf * 16 + kc * 4 + j;
            bool ok = row < NN;
            float s = 0.f, d = 0.f;
            #pragma unroll
            for (int nf = 0; nf < 4; nf++) {
                int col = n0 + wc * 64 + nf * 16 + fr;
                float v = acc[mf][nf][j];
                if (MODE == 1) {
                    v = fmaxf(v + cb[col], 0.f);
                    if (ok) out[(size_t)row * HID + col] = v;
                }
                if (FATTN) {
                    s += v * asv[nf]; d += v * adv[nf];
                    if (ok) xhb[(size_t)row * HID + col] = (bf16_t)v;  // bf16 gather table
                }
            }
            if (FATTN) {
                #pragma unroll
                for (int off = 1; off < 16; off <<= 1) {
                    s += __shfl_xor(s, off);
                    d += __shfl_xor(d, off);
                }
                if (ok && fr == 0) {
                    al_s[row * 4 + head] = s;
                    al_d[row * 4 + head] = d;
                }
            }
        }
    }
}

// ---------------------------------------------------------------------------
// CSR build (by destination)
__global__ void deg_kernel(const int* __restrict__ ei, int* __restrict__ deg) {
    int e = blockIdx.x * 256 + threadIdx.x;
    if (e < EE) atomicAdd(&deg[ei[EE + e]], 1);
}

constexpr int SCB = 1024;                       // elems per scan block
constexpr int SCN = (NN + SCB - 1) / SCB;       // 49

__global__ void scan_pass1(const int* __restrict__ deg, int* __restrict__ bsum) {
    int b = blockIdx.x, t = threadIdx.x;
    int base = b * SCB + t * 4;
    int s = 0;
    #pragma unroll
    for (int i = 0; i < 4; i++) { int idx = base + i; if (idx < NN) s += deg[idx]; }
    #pragma unroll
    for (int off = 32; off; off >>= 1) s += __shfl_xor(s, off);
    __shared__ int ps[4];
    if ((t & 63) == 0) ps[t >> 6] = s;
    __syncthreads();
    if (t == 0) bsum[b] = ps[0] + ps[1] + ps[2] + ps[3];
}

__global__ void scan_pass2(int* __restrict__ bsum) {   // 1 block, 64 threads
    int t = threadIdx.x;
    int orig = (t < SCN) ? bsum[t] : 0;
    int v = orig;
    for (int off = 1; off < 64; off <<= 1) {
        int u = __shfl_up(v, off);
        if (t >= off) v += u;
    }
    if (t < SCN) bsum[t] = v - orig;   // exclusive
}

__global__ void scan_pass3(const int* __restrict__ deg, const int* __restrict__ boffs,
                           int* __restrict__ row_ptr, int* __restrict__ cursor) {
    int b = blockIdx.x, t = threadIdx.x;
    int base = b * SCB + t * 4;
    int d[4]; int tot = 0;
    #pragma unroll
    for (int i = 0; i < 4; i++) { int idx = base + i; d[i] = (idx < NN) ? deg[idx] : 0; tot += d[i]; }
    int v = tot;
    for (int off = 1; off < 64; off <<= 1) {
        int u = __shfl_up(v, off);
        if ((t & 63) >= off) v += u;
    }
    __shared__ int wsum[4];
    if ((t & 63) == 63) wsum[t >> 6] = v;
    __syncthreads();
    int woff = 0;
    for (int j = 0; j < (t >> 6); j++) woff += wsum[j];
    int run = boffs[b] + woff + v - tot;
    #pragma unroll
    for (int i = 0; i < 4; i++) {
        int idx = base + i;
        if (idx < NN) {
            cursor[idx] = run;
            run += d[i];
            row_ptr[idx + 1] = run;
        }
    }
    if (b == 0 && t == 0) row_ptr[0] = 0;
}

// fill CSR with materialized src / type / weight (no eid indirection later)
__global__ void fill_kernel(const int* __restrict__ ei, const int* __restrict__ etype,
                            const float* __restrict__ ew, int* __restrict__ cursor,
                            int* __restrict__ csr_src, int* __restrict__ csr_t,
                            float* __restrict__ csr_w) {
    int e = blockIdx.x * 256 + threadIdx.x;
    if (e >= EE) return;
    int dst = ei[EE + e];
    int pos = atomicAdd(&cursor[dst], 1);
    csr_src[pos] = ei[e];
    csr_t[pos]   = etype[e];
    csr_w[pos]   = ew[e];
}

// ---------------------------------------------------------------------------
// h_new[d] = h[d] + sum_{e: dst=d} (h[src_e] + rel_emb[type_e]*w_e)
// lane owns 4 consecutive cols -> float4 loads; 4-deep chunked pipelining;
// rel contribution deferred via per-type wsum.
__global__ void relagg_kernel(const float* __restrict__ h, const int* __restrict__ row_ptr,
                              const int* __restrict__ csr_src, const int* __restrict__ csr_t,
                              const float* __restrict__ csr_w,
                              const float* __restrict__ rel_emb, float* __restrict__ out)
{
    int lane = threadIdx.x & 63, wid = threadIdx.x >> 6;
    int node = blockIdx.x * 4 + wid;
    if (node >= NN) return;
    int c0 = lane * 4;
    f32x4 acc = *(const f32x4*)(h + (size_t)node * HID + c0);
    float wsum[5] = {0.f, 0.f, 0.f, 0.f, 0.f};
    int beg = row_ptr[node], end = row_ptr[node + 1];
    int k = beg;
    for (; k + 4 <= end; k += 4) {
        int s[4], tt[4]; float ww[4];
        #pragma unroll
        for (int j = 0; j < 4; j++) {
            s[j]  = csr_src[k + j];
            tt[j] = csr_t[k + j];
            ww[j] = csr_w[k + j];
        }
        f32x4 xv[4];
        #pragma unroll
        for (int j = 0; j < 4; j++) xv[j] = *(const f32x4*)(h + (size_t)s[j] * HID + c0);
        #pragma unroll
        for (int j = 0; j < 4; j++) {
            acc += xv[j];
            #pragma unroll
            for (int r = 0; r < 5; r++) wsum[r] += (tt[j] == r) ? ww[j] : 0.f;
        }
    }
    for (; k < end; k++) {
        int src = csr_src[k]; int t = csr_t[k]; float w = csr_w[k];
        acc += *(const f32x4*)(h + (size_t)src * HID + c0);
        #pragma unroll
        for (int r = 0; r < 5; r++) wsum[r] += (t == r) ? w : 0.f;
    }
    #pragma unroll
    for (int r = 0; r < 5; r++)
        acc += wsum[r] * *(const f32x4*)(rel_emb + r * HID + c0);
    *(f32x4*)(out + (size_t)node * HID + c0) = acc;
}

// GAT aggregation over bf16 xh gather table. Lane owns 4 consecutive cols
// (all in head lane>>4): one 8B load per row, scalar (m,den) + f32x4 acc.
// Online softmax (branchless), + bias + residual + LayerNorm (+ final proj).
template<int FINAL>
__global__ void gat_kernel(const bf16_t* __restrict__ xhb, const float* __restrict__ al_s,
                           const float* __restrict__ al_d, const int* __restrict__ row_ptr,
                           const int* __restrict__ csr_src, const float* __restrict__ h_res,
                           const float* __restrict__ bias, const float* __restrict__ ln_g,
                           const float* __restrict__ ln_b, float* __restrict__ out,
                           const float* __restrict__ W_out, const float* __restrict__ b_out,
                           float* __restrict__ final_out)
{
    int lane = threadIdx.x & 63, wid = threadIdx.x >> 6;
    int node = blockIdx.x * 4 + wid;
    if (node >= NN) return;
    int hh = lane >> 4;                 // this lane's head
    int c0 = lane * 4;                  // 4 consecutive cols, all head hh

    float ald = al_d[node * 4 + hh];
    float m, den;
    f32x4 acc;

    // self-loop first (initializes the online state)
    {
        float als = al_s[node * 4 + hh];
        float e = als + ald;
        e = (e >= 0.f) ? e : 0.2f * e;
        m = e; den = 1.f;
        acc = ld_bf4(xhb + (size_t)node * HID + c0);
    }

    int beg = row_ptr[node], end = row_ptr[node + 1];
    int k = beg;
    for (; k + 4 <= end; k += 4) {
        int s[4];
        #pragma unroll
        for (int j = 0; j < 4; j++) s[j] = csr_src[k + j];
        float als[4];
        #pragma unroll
        for (int j = 0; j < 4; j++) als[j] = al_s[s[j] * 4 + hh];
        f32x4 xv[4];
        #pragma unroll
        for (int j = 0; j < 4; j++) xv[j] = ld_bf4(xhb + (size_t)s[j] * HID + c0);
        #pragma unroll
        for (int j = 0; j < 4; j++) {
            float e = als[j] + ald;
            e = (e >= 0.f) ? e : 0.2f * e;
            float mn  = fmaxf(m, e);
            float f   = __expf(m - mn);   // ==1 exactly when e<=m
            float wgt = __expf(e - mn);
            m   = mn;
            den = den * f + wgt;
            acc = acc * f + wgt * xv[j];
        }
    }
    for (; k < end; k++) {
        int src = csr_src[k];
        float als = al_s[src * 4 + hh];
        f32x4 xv = ld_bf4(xhb + (size_t)src * HID + c0);
        float e = als + ald;
        e = (e >= 0.f) ? e : 0.2f * e;
        float mn  = fmaxf(m, e);
        float f   = __expf(m - mn);
        float wgt = __expf(e - mn);
        m   = mn;
        den = den * f + wgt;
        acc = acc * f + wgt * xv;
    }

    f32x4 bia = *(const f32x4*)(bias + c0);
    f32x4 res = *(const f32x4*)(h_res + (size_t)node * HID + c0);
    f32x4 z;
    float rd = 1.f / (den + 1e-16f);
    #pragma unroll
    for (int i = 0; i < 4; i++) z[i] = acc[i] * rd + bia[i] + res[i];

    float s = z[0] + z[1] + z[2] + z[3];
    #pragma unroll
    for (int off = 32; off; off >>= 1) s += __shfl_xor(s, off);
    float mean = s * (1.f / 256.f);
    float vp = 0.f;
    #pragma unroll
    for (int i = 0; i < 4; i++) { float d2 = z[i] - mean; vp += d2 * d2; }
    #pragma unroll
    for (int off = 32; off; off >>= 1) vp += __shfl_xor(vp, off);
    float rstd = rsqrtf(vp * (1.f / 256.f) + 1e-5f);

    f32x4 g = *(const f32x4*)(ln_g + c0);
    f32x4 bb = *(const f32x4*)(ln_b + c0);
    if (FINAL) {
        f32x4 wo = *(const f32x4*)(W_out + c0);
        float dot = 0.f;
        #pragma unroll
        for (int i = 0; i < 4; i++)
            dot += ((z[i] - mean) * rstd * g[i] + bb[i]) * wo[i];
        #pragma unroll
        for (int off = 32; off; off >>= 1) dot += __shfl_xor(dot, off);
        if (lane == 0) final_out[node] = dot + b_out[0];
    } else {
        f32x4 o;
        #pragma unroll
        for (int i = 0; i < 4; i++) o[i] = (z[i] - mean) * rstd * g[i] + bb[i];
        *(f32x4*)(out + (size_t)node * HID + c0) = o;
    }
}

// ---------------------------------------------------------------------------
extern "C" void kernel_launch(void* const* d_in, const int* in_sizes, int n_in,
                              void* d_out, int out_size, void* d_ws, size_t ws_size,
                              hipStream_t stream) {
    const float* x       = (const float*)d_in[0];
    const int*   ei      = (const int*)d_in[1];
    const int*   etype   = (const int*)d_in[2];
    const float* ew      = (const float*)d_in[3];
    const float* rel_emb = (const float*)d_in[4];
    const float* W_in    = (const float*)d_in[5];
    const float* b_in    = (const float*)d_in[6];
    const float* W1      = (const float*)d_in[7];
    const float* a1s     = (const float*)d_in[8];
    const float* a1d     = (const float*)d_in[9];
    const float* b1      = (const float*)d_in[10];
    const float* W2      = (const float*)d_in[11];
    const float* a2s     = (const float*)d_in[12];
    const float* a2d     = (const float*)d_in[13];
    const float* b2      = (const float*)d_in[14];
    const float* ln1g    = (const float*)d_in[15];
    const float* ln1b    = (const float*)d_in[16];
    const float* ln2g    = (const float*)d_in[17];
    const float* ln2b    = (const float*)d_in[18];
    const float* W_out   = (const float*)d_in[19];
    const float* b_out   = (const float*)d_in[20];
    float* out = (float*)d_out;

    char* ws = (char*)d_ws;
    auto alloc = [&](size_t bytes) {
        void* p = (void*)ws;
        ws += (bytes + 255) & ~(size_t)255;
        return p;
    };
    float*  bufA     = (float*)alloc((size_t)NN * HID * 4);
    float*  bufB     = (float*)alloc((size_t)NN * HID * 4);
    bf16_t* xhb      = (bf16_t*)alloc((size_t)NN * HID * 2);
    bf16_t* wmh      = (bf16_t*)alloc((size_t)HID * IND * 2);
    bf16_t* wml      = (bf16_t*)alloc((size_t)HID * IND * 2);
    bf16_t* w1h      = (bf16_t*)alloc((size_t)HID * HID * 2);
    bf16_t* w1l      = (bf16_t*)alloc((size_t)HID * HID * 2);
    bf16_t* w2h      = (bf16_t*)alloc((size_t)HID * HID * 2);
    bf16_t* w2l      = (bf16_t*)alloc((size_t)HID * HID * 2);
    float*  cbv      = (float*)alloc(256 * 4);
    float*  stats_s  = (float*)alloc(512 * 4);
    float*  stats_mi = (float*)alloc(512 * 4);
    float*  invnorm  = (float*)alloc((size_t)NN * 4);
    float*  al_s     = (float*)alloc((size_t)NN * 4 * 4);
    float*  al_d     = (float*)alloc((size_t)NN * 4 * 4);
    int*    deg      = (int*)alloc((size_t)NN * 4);
    int*    row_ptr  = (int*)alloc((size_t)(NN + 1) * 4);
    int*    cursor   = (int*)alloc((size_t)NN * 4);
    int*    csr_src  = (int*)alloc((size_t)EE * 4);
    int*    csr_t    = (int*)alloc((size_t)EE * 4);
    float*  csr_w    = (float*)alloc((size_t)EE * 4);
    int*    bsum     = (int*)alloc(64 * 4);

    hipMemsetAsync(stats_s, 0, 512 * 4, stream);
    hipMemsetAsync(deg, 0, (size_t)NN * 4, stream);

    // input feature prep
    colstats_kernel<<<1024, 256, 0, stream>>>(x, stats_s);
    finalize_stats_kernel<<<1, 256, 0, stream>>>(stats_s, stats_mi);
    rownorm_kernel<<<(NN + 3) / 4, 256, 0, stream>>>(x, invnorm);
    prep_w_kernel<<<256, 256, 0, stream>>>(W_in, stats_mi, b_in, wmh, wml, cbv);
    prep_ws_kernel<<<256, 256, 0, stream>>>(W1, w1h, w1l);
    prep_ws_kernel<<<256, 256, 0, stream>>>(W2, w2h, w2l);

    // CSR build
    deg_kernel<<<(EE + 255) / 256, 256, 0, stream>>>(ei, deg);
    scan_pass1<<<SCN, 256, 0, stream>>>(deg, bsum);
    scan_pass2<<<1, 64, 0, stream>>>(bsum);
    scan_pass3<<<SCN, 256, 0, stream>>>(deg, bsum, row_ptr, cursor);
    fill_kernel<<<(EE + 255) / 256, 256, 0, stream>>>(ei, etype, ew, cursor,
                                                      csr_src, csr_t, csr_w);

    dim3 g1((NN + 127) / 128, 2);

    // h0 = relu(xin @ W_in^T + b_in)  -> bufA (fp32)
    gemm_mfma_kernel<1, 1024, 0><<<g1, 256, 0, stream>>>(
        x, wmh, wml, cbv, invnorm, nullptr, nullptr, bufA, nullptr, nullptr, nullptr);

    int nodeBlocks = (NN + 3) / 4;

    // relational aggregation -> bufB (fp32)
    relagg_kernel<<<nodeBlocks, 256, 0, stream>>>(bufA, row_ptr, csr_src, csr_t, csr_w,
                                                  rel_emb, bufB);

    // ---- GAT layer 1 (xh GEMM -> bf16 table + fused attention logits) ----
    gemm_mfma_kernel<0, 256, 1><<<g1, 256, 0, stream>>>(
        bufB, w1h, w1l, nullptr, nullptr, a1s, a1d, nullptr, xhb, al_s, al_d);
    gat_kernel<0><<<nodeBlocks, 256, 0, stream>>>(xhb, al_s, al_d, row_ptr, csr_src,
                                                  bufB, b1, ln1g, ln1b, bufA,
                                                  nullptr, nullptr, nullptr);

    // ---- GAT layer 2 (final projection fused) ----
    gemm_mfma_kernel<0, 256, 1><<<g1, 256, 0, stream>>>(
        bufA, w2h, w2l, nullptr, nullptr, a2s, a2d, nullptr, xhb, al_s, al_d);
    gat_kernel<1><<<nodeBlocks, 256, 0, stream>>>(xhb, al_s, al_d, row_ptr, csr_src,
                                                  bufA, b2, ln2g, ln2b, nullptr,
                                                  W_out, b_out, out);
}

// Round 10
// 423.011 us; speedup vs baseline: 1.1896x; 1.0526x over previous
//
#include <hip/hip_runtime.h>
#include <math.h>

// Problem constants (from reference)
constexpr int NN   = 50000;   // nodes
constexpr int EE   = 300000;  // edges
constexpr int IND  = 1024;    // IN_DIM
constexpr int CODE = 768;     // CODE_DIM
constexpr int HID  = 256;

typedef __bf16 bf16_t;
typedef bf16_t bf16x4 __attribute__((ext_vector_type(4)));
typedef bf16_t bf16x8 __attribute__((ext_vector_type(8)));
typedef float  f32x4  __attribute__((ext_vector_type(4)));

__device__ __forceinline__ f32x4 mfma16(bf16x8 a, bf16x8 b, f32x4 c) {
    return __builtin_amdgcn_mfma_f32_16x16x32_bf16(a, b, c, 0, 0, 0);
}

// async global->LDS, 16B per lane, wave-uniform LDS base + lane*16
#define GLOAD_LDS16(gp, lp) __builtin_amdgcn_global_load_lds(                         \
    (__attribute__((address_space(1))) void*)(gp),                                    \
    (__attribute__((address_space(3))) void*)(lp), 16, 0, 0)

// convert 8 fp32 -> hi/lo bf16 split (v = hi + lo, |lo| ~ 2^-8 |v|)
__device__ __forceinline__ void cvt_split(f32x4 u0, f32x4 u1, bf16x8& hi, bf16x8& lo) {
    #pragma unroll
    for (int i = 0; i < 4; i++) {
        bf16_t h0 = (bf16_t)u0[i];
        hi[i]     = h0;
        lo[i]     = (bf16_t)(u0[i] - (float)h0);
        bf16_t h1 = (bf16_t)u1[i];
        hi[4 + i] = h1;
        lo[4 + i] = (bf16_t)(u1[i] - (float)h1);
    }
}

// convert 8 fp32 -> bf16 (hi only)
__device__ __forceinline__ bf16x8 cvt_hi(f32x4 u0, f32x4 u1) {
    bf16x8 h;
    #pragma unroll
    for (int i = 0; i < 4; i++) {
        h[i]     = (bf16_t)u0[i];
        h[4 + i] = (bf16_t)u1[i];
    }
    return h;
}

// load 4 consecutive bf16 -> f32x4
__device__ __forceinline__ f32x4 ld_bf4(const bf16_t* p) {
    bf16x4 v = *(const bf16x4*)p;
    f32x4 r;
    r[0] = (float)v[0]; r[1] = (float)v[1]; r[2] = (float)v[2]; r[3] = (float)v[3];
    return r;
}

// ---------------------------------------------------------------------------
// Stage 1: per-column sum/sumsq of x[:, 768:1024]
__global__ void colstats_kernel(const float* __restrict__ x, float* __restrict__ sums) {
    int col = threadIdx.x;             // 0..255
    float s = 0.f, s2 = 0.f;
    for (int row = blockIdx.x; row < NN; row += gridDim.x) {
        float v = x[(size_t)row * IND + CODE + col];
        s += v; s2 += v * v;
    }
    atomicAdd(&sums[col], s);
    atomicAdd(&sums[256 + col], s2);
}

// Stage 2: per-row inverse L2 norm of x[:, 0:768]
__global__ void rownorm_kernel(const float* __restrict__ x, float* __restrict__ invnorm) {
    int lane = threadIdx.x & 63;
    int wid  = threadIdx.x >> 6;
    int row  = blockIdx.x * 4 + wid;
    if (row >= NN) return;
    const float4* x4 = (const float4*)(x + (size_t)row * IND);
    float s = 0.f;
    #pragma unroll
    for (int i = 0; i < 3; i++) {
        float4 v = x4[lane + i * 64];
        s += v.x * v.x + v.y * v.y + v.z * v.z + v.w * v.w;
    }
    #pragma unroll
    for (int off = 32; off; off >>= 1) s += __shfl_xor(s, off);
    if (lane == 0) invnorm[row] = 1.f / fmaxf(sqrtf(s), 1e-12f);
}

// Build Wmod (GEMM-ordered, numeric part pre-scaled) as bf16 (hi only; MODE1
// compensates with the A-side lo term) and cb = b - d. Stats finalization
// (mean/invstd from sums) is recomputed per thread (2 KB read, trivial).
__global__ void prep_w_kernel(const float* __restrict__ W, const float* __restrict__ sums,
                              const float* __restrict__ b_in, bf16_t* __restrict__ Wh,
                              float* __restrict__ cb)
{
    int c = blockIdx.x, t = threadIdx.x;      // 256 blocks x 256 threads
    float mean = sums[t] / (float)NN;
    float var  = (sums[256 + t] - (float)NN * mean * mean) / (float)(NN - 1);
    float sd   = fmaxf(sqrtf(fmaxf(var, 0.f)), 1e-6f);
    float invstd = 1.f / sd;

    const float* wr = W + (size_t)c * IND;
    bf16_t* wh = Wh + (size_t)c * IND;
    for (int k = t; k < 768; k += 256) wh[k] = (bf16_t)wr[256 + k];
    wh[768 + t] = (bf16_t)(wr[t] * invstd);

    float p = wr[t] * invstd * mean;
    #pragma unroll
    for (int off = 32; off; off >>= 1) p += __shfl_xor(p, off);
    __shared__ float ps[4];
    if ((t & 63) == 0) ps[t >> 6] = p;
    __syncthreads();
    if (t == 0) cb[c] = b_in[c] - (ps[0] + ps[1] + ps[2] + ps[3]);
}

// both small weights (256x256) -> bf16 in one launch
__global__ void prep_ws_kernel(const float* __restrict__ W1, const float* __restrict__ W2,
                               bf16_t* __restrict__ Wh1, bf16_t* __restrict__ Wh2)
{
    int c = blockIdx.x, t = threadIdx.x;
    if (c < 256) Wh1[(size_t)c * 256 + t] = (bf16_t)W1[(size_t)c * 256 + t];
    else {
        int cc = c - 256;
        Wh2[(size_t)cc * 256 + t] = (bf16_t)W2[(size_t)cc * 256 + t];
    }
}

// ---------------------------------------------------------------------------
// MFMA GEMM, global_load_lds staging, double-buffered, 48.5 KB LDS -> 3 blk/CU.
// MODE 1: A = x, B = Wmod(bf16); 2-term split (ahi*b + alo*b) for fp32-level
//         accuracy; acc *= invnorm[row] at tile 24; epilogue relu(acc+cb).
// MODE 0 (+FATTN): pure bf16 (1 MFMA) - output is bf16-quantized anyway;
//         epilogue computes attention logits al_s/al_d (wave == one head)
//         and writes xh as bf16 gather table.
// Tile 128x128, BK=32, 256 threads = 4 waves (2x2), 64x64 per wave.

__device__ __forceinline__ void stage_a(const float* __restrict__ src, int ldk,
                                        int rowbase, int maxrow, int k0,
                                        float* ldsbuf, int tid) {
    int w = tid >> 6, l = tid & 63;
    int lr = l >> 3, lc = l & 7;
    int g  = lc ^ lr;                      // swizzled source chunk (row&7 == lr)
    #pragma unroll
    for (int i = 0; i < 4; i++) {
        int rloc = i * 32 + w * 8;
        float* dst = ldsbuf + rloc * 32;   // wave-uniform base
        int row = rowbase + rloc + lr;
        if (row > maxrow) row = maxrow;
        const float* gp = src + (size_t)row * ldk + k0 + g * 4;
        GLOAD_LDS16(gp, dst);
    }
}

// stage 128x32 bf16 tile; LDS slot p of col holds global chunk p^((col>>1)&3)
__device__ __forceinline__ void stage_b(const bf16_t* __restrict__ src, int n0, int ldk,
                                        int k0, bf16_t* buf, int tid) {
    int w = tid >> 6, l = tid & 63;
    #pragma unroll
    for (int i = 0; i < 2; i++) {
        int gbase = w * 128 + i * 64;
        bf16_t* dst = buf + gbase * 8;     // wave-uniform base (granule*8 bf16)
        int g = gbase + l;
        int col = g >> 2, p = g & 3;
        int gs = p ^ ((col >> 1) & 3);
        const bf16_t* gp = src + (size_t)(n0 + col) * ldk + k0 + gs * 8;
        GLOAD_LDS16(gp, dst);
    }
}

template<int MODE, int K, int FATTN>
__global__ __launch_bounds__(256) void gemm_mfma_kernel(
    const float* __restrict__ A, const bf16_t* __restrict__ Bh,
    const float* __restrict__ cb, const float* __restrict__ invnorm,
    const float* __restrict__ a_src, const float* __restrict__ a_dst,
    float* __restrict__ out, bf16_t* __restrict__ xhb,
    float* __restrict__ al_s, float* __restrict__ al_d)
{
    __shared__ float  As[2][128 * 32];                         // 32 KB
    __shared__ bf16_t Bhs[2][128 * 32];                        // 16 KB
    __shared__ float inv_s[128];
    constexpr int NT = K / 32;

    int tid  = threadIdx.x;
    int lane = tid & 63;
    int w    = tid >> 6;
    int wr   = w >> 1, wc = w & 1;
    int r0   = blockIdx.x * 128, n0 = blockIdx.y * 128;

    if (MODE == 1 && tid < 128) {
        int r = r0 + tid;
        inv_s[tid] = (r < NN) ? invnorm[r] : 1.f;
    }

    f32x4 acc[4][4];
    #pragma unroll
    for (int i = 0; i < 4; i++)
        #pragma unroll
        for (int j = 0; j < 4; j++) acc[i][j] = (f32x4)0.f;

    int kc = lane >> 4, fr = lane & 15;    // kc doubles as fq in epilogue

    stage_a(A, K, r0, NN - 1, 0, As[0], tid);
    stage_b(Bh, n0, K, 0, Bhs[0], tid);
    __syncthreads();   // vmcnt(0) drain: tile 0 resident

    for (int t = 0; t < NT; ++t) {
        int buf = t & 1;
        if (t + 1 < NT) {   // issue next tile; lands during this compute phase
            stage_a(A, K, r0, NN - 1, (t + 1) * 32, As[buf ^ 1], tid);
            stage_b(Bh, n0, K, (t + 1) * 32, Bhs[buf ^ 1], tid);
        }
        if (MODE == 1 && t == 24) {  // kap==768: close code segment, scale by row norm
            #pragma unroll
            for (int mf = 0; mf < 4; mf++) {
                f32x4 iv = *(const f32x4*)&inv_s[wr * 64 + mf * 16 + kc * 4];
                #pragma unroll
                for (int nf = 0; nf < 4; nf++)
                    #pragma unroll
                    for (int j = 0; j < 4; j++) acc[mf][nf][j] *= iv[j];
            }
        }
        // ---- fragments + MFMA ----
        const float*  Ab = As[buf];
        const bf16_t* Hb = Bhs[buf];
        bf16x8 ahi[4], alo[4];
        #pragma unroll
        for (int mf = 0; mf < 4; mf++) {
            int r  = wr * 64 + mf * 16 + fr;
            int rb = r * 32, r7 = r & 7;
            f32x4 u0 = *(const f32x4*)&Ab[rb + (((2 * kc + 0) ^ r7) << 2)];
            f32x4 u1 = *(const f32x4*)&Ab[rb + (((2 * kc + 1) ^ r7) << 2)];
            if (MODE == 1) cvt_split(u0, u1, ahi[mf], alo[mf]);
            else           ahi[mf] = cvt_hi(u0, u1);
        }
        #pragma unroll
        for (int nf = 0; nf < 4; nf++) {
            int c  = wc * 64 + nf * 16 + fr;
            int pr = kc ^ ((c >> 1) & 3);
            bf16x8 bhi = *(const bf16x8*)&Hb[c * 32 + pr * 8];
            #pragma unroll
            for (int mf = 0; mf < 4; mf++) {
                acc[mf][nf] = mfma16(ahi[mf], bhi, acc[mf][nf]);
                if (MODE == 1) acc[mf][nf] = mfma16(alo[mf], bhi, acc[mf][nf]);
            }
        }
        __syncthreads();  // tile t+1 landed; all reads of buf done
    }

    // ---- epilogue ----
    int head = blockIdx.y * 2 + wc;
    float asv[4], adv[4];
    if (FATTN) {
        #pragma unroll
        for (int nf = 0; nf < 4; nf++) {
            asv[nf] = a_src[head * 64 + nf * 16 + fr];
            adv[nf] = a_dst[head * 64 + nf * 16 + fr];
        }
    }
    #pragma unroll
    for (int mf = 0; mf < 4; mf++) {
        #pragma unroll
        for (int j = 0; j < 4; j++) {
            int row = r0 + wr * 64 + mf * 16 + kc * 4 + j;
            bool ok = row < NN;
            float s = 0.f, d = 0.f;
            #pragma unroll
            for (int nf = 0; nf < 4; nf++) {
                int col = n0 + wc * 64 + nf * 16 + fr;
                float v = acc[mf][nf][j];
                if (MODE == 1) {
                    v = fmaxf(v + cb[col], 0.f);
                    if (ok) out[(size_t)row * HID + col] = v;
                }
                if (FATTN) {
                    s += v * asv[nf]; d += v * adv[nf];
                    if (ok) xhb[(size_t)row * HID + col] = (bf16_t)v;  // bf16 gather table
                }
            }
            if (FATTN) {
                #pragma unroll
                for (int off = 1; off < 16; off <<= 1) {
                    s += __shfl_xor(s, off);
                    d += __shfl_xor(d, off);
                }
                if (ok && fr == 0) {
                    al_s[row * 4 + head] = s;
                    al_d[row * 4 + head] = d;
                }
            }
        }
    }
}

// ---------------------------------------------------------------------------
// CSR build (by destination)
__global__ void deg_kernel(const int* __restrict__ ei, int* __restrict__ deg) {
    int e = blockIdx.x * 256 + threadIdx.x;
    if (e < EE) atomicAdd(&deg[ei[EE + e]], 1);
}

constexpr int SCB = 1024;                       // elems per scan block
constexpr int SCN = (NN + SCB - 1) / SCB;       // 49

__global__ void scan_pass1(const int* __restrict__ deg, int* __restrict__ bsum) {
    int b = blockIdx.x, t = threadIdx.x;
    int base = b * SCB + t * 4;
    int s = 0;
    #pragma unroll
    for (int i = 0; i < 4; i++) { int idx = base + i; if (idx < NN) s += deg[idx]; }
    #pragma unroll
    for (int off = 32; off; off >>= 1) s += __shfl_xor(s, off);
    __shared__ int ps[4];
    if ((t & 63) == 0) ps[t >> 6] = s;
    __syncthreads();
    if (t == 0) bsum[b] = ps[0] + ps[1] + ps[2] + ps[3];
}

__global__ void scan_pass2(int* __restrict__ bsum) {   // 1 block, 64 threads
    int t = threadIdx.x;
    int orig = (t < SCN) ? bsum[t] : 0;
    int v = orig;
    for (int off = 1; off < 64; off <<= 1) {
        int u = __shfl_up(v, off);
        if (t >= off) v += u;
    }
    if (t < SCN) bsum[t] = v - orig;   // exclusive
}

__global__ void scan_pass3(const int* __restrict__ deg, const int* __restrict__ boffs,
                           int* __restrict__ row_ptr, int* __restrict__ cursor) {
    int b = blockIdx.x, t = threadIdx.x;
    int base = b * SCB + t * 4;
    int d[4]; int tot = 0;
    #pragma unroll
    for (int i = 0; i < 4; i++) { int idx = base + i; d[i] = (idx < NN) ? deg[idx] : 0; tot += d[i]; }
    int v = tot;
    for (int off = 1; off < 64; off <<= 1) {
        int u = __shfl_up(v, off);
        if ((t & 63) >= off) v += u;
    }
    __shared__ int wsum[4];
    if ((t & 63) == 63) wsum[t >> 6] = v;
    __syncthreads();
    int woff = 0;
    for (int j = 0; j < (t >> 6); j++) woff += wsum[j];
    int run = boffs[b] + woff + v - tot;
    #pragma unroll
    for (int i = 0; i < 4; i++) {
        int idx = base + i;
        if (idx < NN) {
            cursor[idx] = run;
            run += d[i];
            row_ptr[idx + 1] = run;
        }
    }
    if (b == 0 && t == 0) row_ptr[0] = 0;
}

// fill CSR with materialized src / type / weight (no eid indirection later)
__global__ void fill_kernel(const int* __restrict__ ei, const int* __restrict__ etype,
                            const float* __restrict__ ew, int* __restrict__ cursor,
                            int* __restrict__ csr_src, int* __restrict__ csr_t,
                            float* __restrict__ csr_w) {
    int e = blockIdx.x * 256 + threadIdx.x;
    if (e >= EE) return;
    int dst = ei[EE + e];
    int pos = atomicAdd(&cursor[dst], 1);
    csr_src[pos] = ei[e];
    csr_t[pos]   = etype[e];
    csr_w[pos]   = ew[e];
}

// ---------------------------------------------------------------------------
// h_new[d] = h[d] + sum_{e: dst=d} (h[src_e] + rel_emb[type_e]*w_e)
// lane owns 4 consecutive cols -> float4 loads; 4-deep chunked pipelining;
// rel contribution deferred via per-type wsum.
__global__ void relagg_kernel(const float* __restrict__ h, const int* __restrict__ row_ptr,
                              const int* __restrict__ csr_src, const int* __restrict__ csr_t,
                              const float* __restrict__ csr_w,
                              const float* __restrict__ rel_emb, float* __restrict__ out)
{
    int lane = threadIdx.x & 63, wid = threadIdx.x >> 6;
    int node = blockIdx.x * 4 + wid;
    if (node >= NN) return;
    int c0 = lane * 4;
    f32x4 acc = *(const f32x4*)(h + (size_t)node * HID + c0);
    float wsum[5] = {0.f, 0.f, 0.f, 0.f, 0.f};
    int beg = row_ptr[node], end = row_ptr[node + 1];
    int k = beg;
    for (; k + 4 <= end; k += 4) {
        int s[4], tt[4]; float ww[4];
        #pragma unroll
        for (int j = 0; j < 4; j++) {
            s[j]  = csr_src[k + j];
            tt[j] = csr_t[k + j];
            ww[j] = csr_w[k + j];
        }
        f32x4 xv[4];
        #pragma unroll
        for (int j = 0; j < 4; j++) xv[j] = *(const f32x4*)(h + (size_t)s[j] * HID + c0);
        #pragma unroll
        for (int j = 0; j < 4; j++) {
            acc += xv[j];
            #pragma unroll
            for (int r = 0; r < 5; r++) wsum[r] += (tt[j] == r) ? ww[j] : 0.f;
        }
    }
    for (; k < end; k++) {
        int src = csr_src[k]; int t = csr_t[k]; float w = csr_w[k];
        acc += *(const f32x4*)(h + (size_t)src * HID + c0);
        #pragma unroll
        for (int r = 0; r < 5; r++) wsum[r] += (t == r) ? w : 0.f;
    }
    #pragma unroll
    for (int r = 0; r < 5; r++)
        acc += wsum[r] * *(const f32x4*)(rel_emb + r * HID + c0);
    *(f32x4*)(out + (size_t)node * HID + c0) = acc;
}

// GAT aggregation over bf16 xh gather table. Lane owns 4 consecutive cols
// (all in head lane>>4): one 8B load per row, scalar (m,den) + f32x4 acc.
// Online softmax (branchless), + bias + residual + LayerNorm (+ final proj).
template<int FINAL>
__global__ void gat_kernel(const bf16_t* __restrict__ xhb, const float* __restrict__ al_s,
                           const float* __restrict__ al_d, const int* __restrict__ row_ptr,
                           const int* __restrict__ csr_src, const float* __restrict__ h_res,
                           const float* __restrict__ bias, const float* __restrict__ ln_g,
                           const float* __restrict__ ln_b, float* __restrict__ out,
                           const float* __restrict__ W_out, const float* __restrict__ b_out,
                           float* __restrict__ final_out)
{
    int lane = threadIdx.x & 63, wid = threadIdx.x >> 6;
    int node = blockIdx.x * 4 + wid;
    if (node >= NN) return;
    int hh = lane >> 4;                 // this lane's head
    int c0 = lane * 4;                  // 4 consecutive cols, all head hh

    float ald = al_d[node * 4 + hh];
    float m, den;
    f32x4 acc;

    // self-loop first (initializes the online state)
    {
        float als = al_s[node * 4 + hh];
        float e = als + ald;
        e = (e >= 0.f) ? e : 0.2f * e;
        m = e; den = 1.f;
        acc = ld_bf4(xhb + (size_t)node * HID + c0);
    }

    int beg = row_ptr[node], end = row_ptr[node + 1];
    int k = beg;
    for (; k + 4 <= end; k += 4) {
        int s[4];
        #pragma unroll
        for (int j = 0; j < 4; j++) s[j] = csr_src[k + j];
        float als[4];
        #pragma unroll
        for (int j = 0; j < 4; j++) als[j] = al_s[s[j] * 4 + hh];
        f32x4 xv[4];
        #pragma unroll
        for (int j = 0; j < 4; j++) xv[j] = ld_bf4(xhb + (size_t)s[j] * HID + c0);
        #pragma unroll
        for (int j = 0; j < 4; j++) {
            float e = als[j] + ald;
            e = (e >= 0.f) ? e : 0.2f * e;
            float mn  = fmaxf(m, e);
            float f   = __expf(m - mn);   // ==1 exactly when e<=m
            float wgt = __expf(e - mn);
            m   = mn;
            den = den * f + wgt;
            acc = acc * f + wgt * xv[j];
        }
    }
    for (; k < end; k++) {
        int src = csr_src[k];
        float als = al_s[src * 4 + hh];
        f32x4 xv = ld_bf4(xhb + (size_t)src * HID + c0);
        float e = als + ald;
        e = (e >= 0.f) ? e : 0.2f * e;
        float mn  = fmaxf(m, e);
        float f   = __expf(m - mn);
        float wgt = __expf(e - mn);
        m   = mn;
        den = den * f + wgt;
        acc = acc * f + wgt * xv;
    }

    f32x4 bia = *(const f32x4*)(bias + c0);
    f32x4 res = *(const f32x4*)(h_res + (size_t)node * HID + c0);
    f32x4 z;
    float rd = 1.f / (den + 1e-16f);
    #pragma unroll
    for (int i = 0; i < 4; i++) z[i] = acc[i] * rd + bia[i] + res[i];

    float s = z[0] + z[1] + z[2] + z[3];
    #pragma unroll
    for (int off = 32; off; off >>= 1) s += __shfl_xor(s, off);
    float mean = s * (1.f / 256.f);
    float vp = 0.f;
    #pragma unroll
    for (int i = 0; i < 4; i++) { float d2 = z[i] - mean; vp += d2 * d2; }
    #pragma unroll
    for (int off = 32; off; off >>= 1) vp += __shfl_xor(vp, off);
    float rstd = rsqrtf(vp * (1.f / 256.f) + 1e-5f);

    f32x4 g = *(const f32x4*)(ln_g + c0);
    f32x4 bb = *(const f32x4*)(ln_b + c0);
    if (FINAL) {
        f32x4 wo = *(const f32x4*)(W_out + c0);
        float dot = 0.f;
        #pragma unroll
        for (int i = 0; i < 4; i++)
            dot += ((z[i] - mean) * rstd * g[i] + bb[i]) * wo[i];
        #pragma unroll
        for (int off = 32; off; off >>= 1) dot += __shfl_xor(dot, off);
        if (lane == 0) final_out[node] = dot + b_out[0];
    } else {
        f32x4 o;
        #pragma unroll
        for (int i = 0; i < 4; i++) o[i] = (z[i] - mean) * rstd * g[i] + bb[i];
        *(f32x4*)(out + (size_t)node * HID + c0) = o;
    }
}

// ---------------------------------------------------------------------------
extern "C" void kernel_launch(void* const* d_in, const int* in_sizes, int n_in,
                              void* d_out, int out_size, void* d_ws, size_t ws_size,
                              hipStream_t stream) {
    const float* x       = (const float*)d_in[0];
    const int*   ei      = (const int*)d_in[1];
    const int*   etype   = (const int*)d_in[2];
    const float* ew      = (const float*)d_in[3];
    const float* rel_emb = (const float*)d_in[4];
    const float* W_in    = (const float*)d_in[5];
    const float* b_in    = (const float*)d_in[6];
    const float* W1      = (const float*)d_in[7];
    const float* a1s     = (const float*)d_in[8];
    const float* a1d     = (const float*)d_in[9];
    const float* b1      = (const float*)d_in[10];
    const float* W2      = (const float*)d_in[11];
    const float* a2s     = (const float*)d_in[12];
    const float* a2d     = (const float*)d_in[13];
    const float* b2      = (const float*)d_in[14];
    const float* ln1g    = (const float*)d_in[15];
    const float* ln1b    = (const float*)d_in[16];
    const float* ln2g    = (const float*)d_in[17];
    const float* ln2b    = (const float*)d_in[18];
    const float* W_out   = (const float*)d_in[19];
    const float* b_out   = (const float*)d_in[20];
    float* out = (float*)d_out;

    char* ws = (char*)d_ws;
    auto alloc = [&](size_t bytes) {
        void* p = (void*)ws;
        ws += (bytes + 255) & ~(size_t)255;
        return p;
    };
    float*  bufA     = (float*)alloc((size_t)NN * HID * 4);
    float*  bufB     = (float*)alloc((size_t)NN * HID * 4);
    bf16_t* xhb      = (bf16_t*)alloc((size_t)NN * HID * 2);
    bf16_t* wmh      = (bf16_t*)alloc((size_t)HID * IND * 2);
    bf16_t* w1h      = (bf16_t*)alloc((size_t)HID * HID * 2);
    bf16_t* w2h      = (bf16_t*)alloc((size_t)HID * HID * 2);
    float*  cbv      = (float*)alloc(256 * 4);
    float*  stats_s  = (float*)alloc(512 * 4);
    float*  invnorm  = (float*)alloc((size_t)NN * 4);
    float*  al_s     = (float*)alloc((size_t)NN * 4 * 4);
    float*  al_d     = (float*)alloc((size_t)NN * 4 * 4);
    int*    deg      = (int*)alloc((size_t)NN * 4);
    int*    row_ptr  = (int*)alloc((size_t)(NN + 1) * 4);
    int*    cursor   = (int*)alloc((size_t)NN * 4);
    int*    csr_src  = (int*)alloc((size_t)EE * 4);
    int*    csr_t    = (int*)alloc((size_t)EE * 4);
    float*  csr_w    = (float*)alloc((size_t)EE * 4);
    int*    bsum     = (int*)alloc(64 * 4);

    hipMemsetAsync(stats_s, 0, 512 * 4, stream);
    hipMemsetAsync(deg, 0, (size_t)NN * 4, stream);

    // input feature prep
    colstats_kernel<<<1024, 256, 0, stream>>>(x, stats_s);
    rownorm_kernel<<<(NN + 3) / 4, 256, 0, stream>>>(x, invnorm);
    prep_w_kernel<<<256, 256, 0, stream>>>(W_in, stats_s, b_in, wmh, cbv);
    prep_ws_kernel<<<512, 256, 0, stream>>>(W1, W2, w1h, w2h);

    // CSR build
    deg_kernel<<<(EE + 255) / 256, 256, 0, stream>>>(ei, deg);
    scan_pass1<<<SCN, 256, 0, stream>>>(deg, bsum);
    scan_pass2<<<1, 64, 0, stream>>>(bsum);
    scan_pass3<<<SCN, 256, 0, stream>>>(deg, bsum, row_ptr, cursor);
    fill_kernel<<<(EE + 255) / 256, 256, 0, stream>>>(ei, etype, ew, cursor,
                                                      csr_src, csr_t, csr_w);

    dim3 g1((NN + 127) / 128, 2);

    // h0 = relu(xin @ W_in^T + b_in)  -> bufA (fp32)
    gemm_mfma_kernel<1, 1024, 0><<<g1, 256, 0, stream>>>(
        x, wmh, cbv, invnorm, nullptr, nullptr, bufA, nullptr, nullptr, nullptr);

    int nodeBlocks = (NN + 3) / 4;

    // relational aggregation -> bufB (fp32)
    relagg_kernel<<<nodeBlocks, 256, 0, stream>>>(bufA, row_ptr, csr_src, csr_t, csr_w,
                                                  rel_emb, bufB);

    // ---- GAT layer 1 (xh GEMM -> bf16 table + fused attention logits) ----
    gemm_mfma_kernel<0, 256, 1><<<g1, 256, 0, stream>>>(
        bufB, w1h, nullptr, nullptr, a1s, a1d, nullptr, xhb, al_s, al_d);
    gat_kernel<0><<<nodeBlocks, 256, 0, stream>>>(xhb, al_s, al_d, row_ptr, csr_src,
                                                  bufB, b1, ln1g, ln1b, bufA,
                                                  nullptr, nullptr, nullptr);

    // ---- GAT layer 2 (final projection fused) ----
    gemm_mfma_kernel<0, 256, 1><<<g1, 256, 0, stream>>>(
        bufA, w2h, nullptr, nullptr, a2s, a2d, nullptr, xhb, al_s, al_d);
    gat_kernel<1><<<nodeBlocks, 256, 0, stream>>>(xhb, al_s, al_d, row_ptr, csr_src,
                                                  bufA, b2, ln2g, ln2b, nullptr,
                                                  W_out, b_out, out);
}